// Round 10
// baseline (598.320 us; speedup 1.0000x reference)
//
#include <hip/hip_runtime.h>

#define NN 50000
#define NE 1600000
#define NR 8
#define ND 128
#define NL 3
#define RN (NR * NN)
#define LN_EPS 1e-5f
#define PADF 132   // f32 elems per epilogue scratch row (8448 B per wave region)

// binning
#define NBKT 196          // seg >> 11 -> 196 coarse buckets (2048 segs each)
#define BSH 11
#define STRIDE_PB 10240   // stage dwords per bucket (mean 8163, +23 sigma; verified r5/r6)
#define BIN_BLOCKS 1000   // r10: 2x blocks (1600 edges each) for TLP
#define EPB 1600          // edges per binA block
#define I4PB 400          // int4 loads per stream per block
#define MM_BLOCKS_SA ((NN + 127) / 128)      // 391 standalone (128 rows, NG=2)
#define MM_BLOCKS_FU ((NN + 63) / 64)        // 782 in fused launch (64 rows, NG=1)

// prep region sizes (bcur zeroed via hipMemsetAsync, NOT in-grid: r7 crash was
// binA blocks racing the prep block that zeroed bcur — block order is undefined)
#define PREP_G (NN * 64)        // gather dwords
#define PREP_W (27 * 16384)     // wprep elems
#define PREP_TOT (PREP_G + PREP_W)
#define PREP_BLOCKS ((PREP_TOT + 255) / 256)

// workspace layout
#define WS_H    0
#define WS_ROW  14400000
#define WS_BCUR 16000064     // 784 B in rowstart region slack (rowstart ends 16,000,004)
#define WS_ADJ  16004096
#define WS_WB   22404096
#define WS_BIG  23288832
#define WS_NEED_NEW (23288832ULL + 9ULL * NN * 256)   // hr = 9 tables -> 138.5 MB
// stage lives in d_out (25.6 MB, dead until the last aggln overwrites it fully)

typedef __attribute__((ext_vector_type(8))) short short8;
typedef __attribute__((ext_vector_type(4))) float float4v;
typedef __attribute__((ext_vector_type(4))) unsigned uint4v;

__device__ __forceinline__ float bflo(unsigned u) { return __uint_as_float(u << 16); }
__device__ __forceinline__ float bfhi(unsigned u) { return __uint_as_float(u & 0xFFFF0000u); }
__device__ __forceinline__ unsigned f2bf(float f) {
    unsigned u = __float_as_uint(f);
    return (u + 0x7FFFu + ((u >> 16) & 1u)) >> 16;   // RNE
}
__device__ __forceinline__ unsigned pack2(float lo, float hi) {
    return f2bf(lo) | (f2bf(hi) << 16);
}

// ---- launch 1: binA (blocks [0,1000)) || prep (h gather | wprep) ----
// bcur pre-zeroed on-stream (memset) so binA's atomicAdds are safe.
__global__ __launch_bounds__(256) void k_prepbin(const int* __restrict__ x,
                                                 const float* __restrict__ emb,
                                                 const float* __restrict__ w_rel,
                                                 const float* __restrict__ w_root,
                                                 const int* __restrict__ src,
                                                 const int* __restrict__ dst,
                                                 const int* __restrict__ et,
                                                 unsigned* __restrict__ h,
                                                 unsigned short* __restrict__ wb,
                                                 int* __restrict__ bcur,
                                                 unsigned* __restrict__ stage) {
    __shared__ int lcnt[256];
    __shared__ int loff[256];
    __shared__ int lcur[256];
    __shared__ int sbase[256];
    __shared__ int tmp[256];
    __shared__ unsigned srt[EPB];          // 6.4 KB
    __shared__ unsigned char bkt[EPB];     // 1.6 KB

    int tid = threadIdx.x;
    if (blockIdx.x >= BIN_BLOCKS) {
        // ---- prep path ----
        int i = (blockIdx.x - BIN_BLOCKS) * 256 + tid;
        if (i < PREP_G) {
            int n = i >> 6, dw = i & 63;
            float2 v = *(const float2*)&emb[(size_t)x[n] * ND + 2 * dw];
            h[i] = pack2(v.x, v.y);
            return;
        }
        i -= PREP_G;
        if (i < PREP_W) {
            int m = i >> 14;
            int idx = i & 16383;
            int j = idx & 7;
            int lane = (idx >> 3) & 63;
            int ft = (idx >> 9) & 7;
            int kk = idx >> 12;
            int row = kk * 32 + (lane >> 4) * 8 + j;
            int col = ft * 16 + (lane & 15);
            const float* W = (m < 24) ? (w_rel + (size_t)m * 16384)
                                      : (w_root + (size_t)(m - 24) * 16384);
            wb[i] = (unsigned short)f2bf(W[row * ND + col]);
        }
        return;
    }

    // ---- binA path: per-block LDS counting sort by coarse bucket ----
    lcnt[tid] = 0;
    __syncthreads();

    int base4 = blockIdx.x * I4PB;
    const int4* s4p = (const int4*)src;
    const int4* d4p = (const int4*)dst;
    const int4* t4p = (const int4*)et;

    for (int i4 = tid; i4 < I4PB; i4 += 256) {
        int4 d4 = d4p[base4 + i4];
        int4 t4 = t4p[base4 + i4];
        atomicAdd(&lcnt[(t4.x * NN + d4.x) >> BSH], 1);
        atomicAdd(&lcnt[(t4.y * NN + d4.y) >> BSH], 1);
        atomicAdd(&lcnt[(t4.z * NN + d4.z) >> BSH], 1);
        atomicAdd(&lcnt[(t4.w * NN + d4.w) >> BSH], 1);
    }
    __syncthreads();
    int own = lcnt[tid];
    tmp[tid] = own;
    __syncthreads();
    for (int off = 1; off < 256; off <<= 1) {
        int v = (tid >= off) ? tmp[tid - off] : 0;
        __syncthreads();
        tmp[tid] += v;
        __syncthreads();
    }
    int excl = tmp[tid] - own;
    loff[tid] = excl;
    lcur[tid] = excl;
    if (tid < NBKT) sbase[tid] = atomicAdd(&bcur[tid], own);
    __syncthreads();

    for (int i4 = tid; i4 < I4PB; i4 += 256) {
        int4 s4 = s4p[base4 + i4];
        int4 d4 = d4p[base4 + i4];
        int4 t4 = t4p[base4 + i4];
        int segs[4] = {t4.x * NN + d4.x, t4.y * NN + d4.y,
                       t4.z * NN + d4.z, t4.w * NN + d4.w};
        int srcs[4] = {s4.x, s4.y, s4.z, s4.w};
#pragma unroll
        for (int j = 0; j < 4; j++) {
            int seg = segs[j];
            int b = seg >> BSH;
            unsigned rec = ((unsigned)(seg & 2047) << 16) | (unsigned)srcs[j];
            int pos = atomicAdd(&lcur[b], 1);
            srt[pos] = rec;
            bkt[pos] = (unsigned char)b;
        }
    }
    __syncthreads();
    for (int i = tid; i < EPB; i += 256) {
        int b = bkt[i];
        int idx = sbase[b] + (i - loff[b]);
        if (idx < STRIDE_PB)                     // insurance: degrade, don't fault
            stage[(size_t)b * STRIDE_PB + idx] = srt[i];
    }
}

// ---- shared body for binB (used by fused launch 2 and the fallback) ----
__device__ __forceinline__ void binB_body(const unsigned* __restrict__ stage,
                                          const int* __restrict__ bcur,
                                          int* __restrict__ rowstart,
                                          int* __restrict__ adj,
                                          int b, int tid,
                                          int* tmp, int* lcnt2, int* loff2,
                                          unsigned short* srt2, int* misc) {
    // gbase = exclusive prefix of bucket totals at b
    int bv = (tid < NBKT) ? bcur[tid] : 0;
    tmp[tid] = bv;
    __syncthreads();
    for (int off = 1; off < 256; off <<= 1) {
        int v = (tid >= off) ? tmp[tid - off] : 0;
        __syncthreads();
        tmp[tid] += v;
        __syncthreads();
    }
    if (tid == b) { misc[0] = tmp[tid] - bv; misc[1] = bv; }
    for (int j = tid; j < 2048; j += 256) lcnt2[j] = 0;
    __syncthreads();

    int n = misc[1];
    n = n < STRIDE_PB ? n : STRIDE_PB;           // insurance
    const unsigned* sp = stage + (size_t)b * STRIDE_PB;
    for (int i = tid; i < n; i += 256)
        atomicAdd(&lcnt2[sp[i] >> 16], 1);
    __syncthreads();

    int v8[8];
    int s8 = 0;
    int base8 = tid * 8;
#pragma unroll
    for (int j = 0; j < 8; j++) { v8[j] = lcnt2[base8 + j]; s8 += v8[j]; }
    tmp[tid] = s8;
    __syncthreads();
    for (int off = 1; off < 256; off <<= 1) {
        int v = (tid >= off) ? tmp[tid - off] : 0;
        __syncthreads();
        tmp[tid] += v;
        __syncthreads();
    }
    int run = tmp[tid] - s8;
#pragma unroll
    for (int j = 0; j < 8; j++) { loff2[base8 + j] = run; run += v8[j]; }
    __syncthreads();
    for (int j = tid; j < 2048; j += 256) lcnt2[j] = loff2[j];
    __syncthreads();

    for (int i = tid; i < n; i += 256) {
        unsigned rec = sp[i];
        int pos = atomicAdd(&lcnt2[rec >> 16], 1);
        srt2[pos] = (unsigned short)(rec & 0xFFFFu);
    }
    __syncthreads();

    int gb = misc[0];
    for (int i = tid; i < n; i += 256) adj[gb + i] = (int)srt2[i];
    int segbase = b << BSH;
    for (int j = tid; j < 2048; j += 256) {
        int seg = segbase + j;
        if (seg < RN) rowstart[seg] = gb + loff2[j];
    }
    if (b == NBKT - 1 && tid == 0) rowstart[RN] = NE;
}

typedef unsigned TRarr[16][66];

// ---- shared body for k_mm, NG row-groups (64 rows each) per block.
// NG=2 standalone (halves B-stage L2 traffic, amortizes barriers); NG=1 in
// the fused launch (978 short blocks pack better with binB — r9 showed 391
// long blocks drop fused occupancy to 13%). TR scratch time-shared
// (wave-private, DS ops complete in issue order -> no barrier).
template <int NG>
__device__ __forceinline__ void mm_body(const unsigned* __restrict__ h32,
                                        const unsigned short* __restrict__ wrel,
                                        const unsigned short* __restrict__ wroot,
                                        unsigned* __restrict__ hr,
                                        int mb, int tid,
                                        uint4* SB4, TRarr* TRp) {
    const unsigned short* SBs = (const unsigned short*)SB4;
    int wave = tid >> 6, lane = tid & 63;
    int quad = lane >> 4, l15 = lane & 15;
    int pr = l15 & 1;

    int rbase[NG];
    short8 af[NG][4];
#pragma unroll
    for (int g = 0; g < NG; g++) {
        rbase[g] = mb * (64 * NG) + g * 64 + wave * 16;
        int gi = rbase[g] + l15; gi = gi < NN ? gi : NN - 1;
        const unsigned* H = h32 + (size_t)gi * 64;
#pragma unroll
        for (int kk = 0; kk < 4; kk++)
            af[g][kk] = *(const short8*)&H[kk * 16 + quad * 4];
    }

    for (int m = 0; m < 9; m++) {
        const unsigned short* W = (m < 8) ? (wrel + (size_t)m * 16384) : wroot;
        __syncthreads();
        {
            const uint4* Wg = (const uint4*)W;
#pragma unroll
            for (int i = 0; i < 8; i++) SB4[tid + 256 * i] = Wg[tid + 256 * i];
        }
        __syncthreads();

        float4v ac[NG][8];
#pragma unroll
        for (int g = 0; g < NG; g++)
#pragma unroll
            for (int i = 0; i < 8; i++) ac[g][i] = (float4v){0.f, 0.f, 0.f, 0.f};
#pragma unroll
        for (int kk = 0; kk < 4; kk++) {
#pragma unroll
            for (int ft = 0; ft < 8; ft++) {
                short8 bf = *(const short8*)&SBs[((kk * 8 + ft) * 64 + lane) * 8];
#pragma unroll
                for (int g = 0; g < NG; g++)
                    ac[g][ft] = __builtin_amdgcn_mfma_f32_16x16x32_bf16(af[g][kk], bf, ac[g][ft], 0, 0, 0);
            }
        }

        unsigned* hrm = hr + (size_t)m * NN * 64;
#pragma unroll
        for (int g = 0; g < NG; g++) {
            // pack + wave-private transpose (no barrier: same-wave order)
#pragma unroll
            for (int ft = 0; ft < 8; ft++) {
                float4v part;
#pragma unroll
                for (int rg = 0; rg < 4; rg++) part[rg] = __shfl_xor(ac[g][ft][rg], 1, 64);
                if ((ft & 1) == pr) {
                    int a = l15 >> 1;
#pragma unroll
                    for (int rg = 0; rg < 4; rg++) {
                        float lo = pr ? part[rg] : ac[g][ft][rg];
                        float hi = pr ? ac[g][ft][rg] : part[rg];
                        TRp[wave][quad * 4 + rg][ft * 8 + a] = pack2(lo, hi);
                    }
                }
            }
#pragma unroll
            for (int ps = 0; ps < 4; ps++) {
                int ri = ps * 4 + quad;
                uint4 v = *(const uint4*)&TRp[wave][ri][l15 * 4];
                int row = rbase[g] + ri;
                if (row < NN)
                    *(uint4*)&hrm[(size_t)row * 64 + l15 * 4] = v;
            }
        }
    }
}

// ---- launch 2: binB (blocks [0,196)) || mm layer 0 (blocks [196, 196+782), NG=1) ----
// stage lives in d_out so mm's hr writes (big) cannot race binB's stage reads.
__global__ __launch_bounds__(256) void k_binB_mm(const unsigned* __restrict__ stage,
                                                 const int* __restrict__ bcur,
                                                 int* __restrict__ rowstart,
                                                 int* __restrict__ adj,
                                                 const unsigned* __restrict__ h32,
                                                 const unsigned short* __restrict__ wrel,
                                                 const unsigned short* __restrict__ wroot,
                                                 unsigned* __restrict__ hr) {
    __shared__ uint4 SMEM[3104];   // 49664 B union: binB 37.9 KB | mm 48.5 KB
    int tid = threadIdx.x;
    if (blockIdx.x < NBKT) {
        int* tmp = (int*)SMEM;
        int* lcnt2 = (int*)SMEM + 256;
        int* loff2 = (int*)SMEM + 2304;
        unsigned short* srt2 = (unsigned short*)((int*)SMEM + 4352);
        int* misc = (int*)SMEM + 9472;
        binB_body(stage, bcur, rowstart, adj, blockIdx.x, tid,
                  tmp, lcnt2, loff2, srt2, misc);
    } else {
        mm_body<1>(h32, wrel, wroot, hr, blockIdx.x - NBKT, tid,
                   SMEM, (TRarr*)(SMEM + 2048));
    }
}

// standalone kernels for layers 1,2 (and fallback)
__global__ __launch_bounds__(256) void k_binB(const unsigned* __restrict__ stage,
                                              const int* __restrict__ bcur,
                                              int* __restrict__ rowstart,
                                              int* __restrict__ adj) {
    __shared__ uint4 SMEM[2369];   // 37904 B
    int tid = threadIdx.x;
    int* tmp = (int*)SMEM;
    int* lcnt2 = (int*)SMEM + 256;
    int* loff2 = (int*)SMEM + 2304;
    unsigned short* srt2 = (unsigned short*)((int*)SMEM + 4352);
    int* misc = (int*)SMEM + 9472;
    binB_body(stage, bcur, rowstart, adj, blockIdx.x, tid,
              tmp, lcnt2, loff2, srt2, misc);
}

__global__ __launch_bounds__(256) void k_mm(const unsigned* __restrict__ h32,
                                            const unsigned short* __restrict__ wrel,
                                            const unsigned short* __restrict__ wroot,
                                            unsigned* __restrict__ hr) {
    __shared__ uint4 SMEM[3104];
    mm_body<2>(h32, wrel, wroot, hr, blockIdx.x, threadIdx.x,
               SMEM, (TRarr*)(SMEM + 2048));
}

// aggln r10: WAVE per node (64 lanes x 1 dword). The old 16-lane-quad layout
// made each wave run the UNION of 4 quads' edge loops (E[max of 4 Poisson(4)]
// ~ 6.6 vs mean 4 -> ~40% partially-masked slots). Per row now: 1 load inst +
// 4 VALU/lane (old: 0.25 shared load + 4 VALU) -- same issue cost, zero
// divergence waste, fewer VGPR. 4 nodes/block, grid NN/4 exact.
__global__ __launch_bounds__(256) void k_aggln(const unsigned* __restrict__ hr,
                                               unsigned* __restrict__ h32,
                                               const int* __restrict__ adj,
                                               const int* __restrict__ rowstart,
                                               const float* __restrict__ bias,
                                               const float* __restrict__ gamma,
                                               const float* __restrict__ beta,
                                               float* __restrict__ out_f,
                                               int add_res, int last) {
    int wave = threadIdx.x >> 6;
    int lane = threadIdx.x & 63;
    int n = blockIdx.x * 4 + wave;               // grid exact: 12500 * 4 = NN

    float t0 = 0.f, t1 = 0.f;
    for (int r = 0; r < NR; r++) {
        int seg = r * NN + n;
        int st = rowstart[seg], en = rowstart[seg + 1];
        st = st < 0 ? 0 : st;
        en = en > NE ? NE : en;
        const unsigned* T = hr + (size_t)r * NN * 64 + lane;

        float a0 = 0.f, a1 = 0.f, b0 = 0.f, b1 = 0.f;
        int p = st;
        for (; p + 3 < en; p += 4) {
            unsigned s0 = (unsigned)adj[p],     s1 = (unsigned)adj[p + 1];
            unsigned s2 = (unsigned)adj[p + 2], s3 = (unsigned)adj[p + 3];
            unsigned u0 = T[(size_t)s0 * 64];
            unsigned u1 = T[(size_t)s1 * 64];
            unsigned u2 = T[(size_t)s2 * 64];
            unsigned u3 = T[(size_t)s3 * 64];
            a0 += bflo(u0); a1 += bfhi(u0);
            b0 += bflo(u1); b1 += bfhi(u1);
            a0 += bflo(u2); a1 += bfhi(u2);
            b0 += bflo(u3); b1 += bfhi(u3);
        }
        for (; p + 1 < en; p += 2) {
            unsigned s0 = (unsigned)adj[p], s1 = (unsigned)adj[p + 1];
            unsigned u0 = T[(size_t)s0 * 64];
            unsigned u1 = T[(size_t)s1 * 64];
            a0 += bflo(u0); a1 += bfhi(u0);
            b0 += bflo(u1); b1 += bfhi(u1);
        }
        if (p < en) {
            unsigned u0 = T[(size_t)(unsigned)adj[p] * 64];
            a0 += bflo(u0); a1 += bfhi(u0);
        }
        int d = en - st;
        float sc = 1.0f / (float)(d > 1 ? d : 1);
        t0 += (a0 + b0) * sc;
        t1 += (a1 + b1) * sc;
    }

    // root row + bias
    {
        unsigned u = hr[((size_t)8 * NN + n) * 64 + lane];
        t0 += bflo(u); t1 += bfhi(u);
    }
    float2 bia = *(const float2*)&bias[2 * lane];
    t0 += bia.x; t1 += bia.y;

    // LN across 128 feats: 2/lane + full-wave shuffle reduce
    float s = t0 + t1;
#pragma unroll
    for (int off = 32; off > 0; off >>= 1) s += __shfl_xor(s, off, 64);
    float mu = s * (1.0f / ND);
    float e0 = t0 - mu, e1 = t1 - mu;
    float vs = e0 * e0 + e1 * e1;
#pragma unroll
    for (int off = 32; off > 0; off >>= 1) vs += __shfl_xor(vs, off, 64);
    float rr = rsqrtf(vs * (1.0f / ND) + LN_EPS);

    float2 gam = *(const float2*)&gamma[2 * lane];
    float2 bet = *(const float2*)&beta[2 * lane];
    float o0 = fmaxf(e0 * rr * gam.x + bet.x, 0.0f);
    float o1 = fmaxf(e1 * rr * gam.y + bet.y, 0.0f);

    if (add_res) {
        unsigned u = h32[(size_t)n * 64 + lane];
        o0 += bflo(u); o1 += bfhi(u);
    }
    if (last) {
        *(float2*)&out_f[(size_t)n * ND + 2 * lane] = make_float2(o0, o1);
    } else {
        h32[(size_t)n * 64 + lane] = pack2(o0, o1);
    }
}

// ---------- FALLBACK PATH (ws too small): proven round-2 agg+gemm ----------

#define AGA(u)                                  \
    a0 += bflo(u.x); a1 += bfhi(u.x);           \
    a2 += bflo(u.y); a3 += bfhi(u.y);           \
    a4 += bflo(u.z); a5 += bfhi(u.z);           \
    a6 += bflo(u.w); a7 += bfhi(u.w);
#define AGC(u)                                  \
    c0 += bflo(u.x); c1 += bfhi(u.x);           \
    c2 += bflo(u.y); c3 += bfhi(u.y);           \
    c4 += bflo(u.z); c5 += bfhi(u.z);           \
    c6 += bflo(u.w); c7 += bfhi(u.w);

__global__ __launch_bounds__(256) void k_agg(const unsigned* __restrict__ h32,
                                             const int* __restrict__ adj,
                                             const int* __restrict__ rowstart,
                                             unsigned* __restrict__ S) {
    int q = (blockIdx.x * 256 + threadIdx.x) >> 4;
    int l15 = threadIdx.x & 15;
    int r = q / NN;
    int n = q - r * NN;
    int st = rowstart[q], en = rowstart[q + 1];
    st = st < 0 ? 0 : st;
    en = en > NE ? NE : en;
    float a0 = 0.f, a1 = 0.f, a2 = 0.f, a3 = 0.f,
          a4 = 0.f, a5 = 0.f, a6 = 0.f, a7 = 0.f;
    float c0 = 0.f, c1 = 0.f, c2 = 0.f, c3 = 0.f,
          c4 = 0.f, c5 = 0.f, c6 = 0.f, c7 = 0.f;
    int p = st;
    for (; p + 3 < en; p += 4) {
        unsigned s0 = (unsigned)adj[p],     s1 = (unsigned)adj[p + 1];
        unsigned s2 = (unsigned)adj[p + 2], s3 = (unsigned)adj[p + 3];
        uint4 u0 = *(const uint4*)&h32[(size_t)s0 * 64 + l15 * 4];
        uint4 u1 = *(const uint4*)&h32[(size_t)s1 * 64 + l15 * 4];
        uint4 u2 = *(const uint4*)&h32[(size_t)s2 * 64 + l15 * 4];
        uint4 u3 = *(const uint4*)&h32[(size_t)s3 * 64 + l15 * 4];
        AGA(u0) AGC(u1) AGA(u2) AGC(u3)
    }
    for (; p < en; p++) {
        unsigned s0 = (unsigned)adj[p];
        uint4 u0 = *(const uint4*)&h32[(size_t)s0 * 64 + l15 * 4];
        AGA(u0)
    }
    int d = en - st;
    float sc = 1.0f / (float)(d > 1 ? d : 1);
    a0 = (a0 + c0) * sc; a1 = (a1 + c1) * sc;
    a2 = (a2 + c2) * sc; a3 = (a3 + c3) * sc;
    a4 = (a4 + c4) * sc; a5 = (a5 + c5) * sc;
    a6 = (a6 + c6) * sc; a7 = (a7 + c7) * sc;
    uint4v w;
    w.x = pack2(a0, a1); w.y = pack2(a2, a3);
    w.z = pack2(a4, a5); w.w = pack2(a6, a7);
    __builtin_nontemporal_store(w, (uint4v*)&S[(size_t)n * 512 + r * 64 + l15 * 4]);
}

__global__ __launch_bounds__(256) void k_gemm(const unsigned* __restrict__ S,
                                              unsigned* __restrict__ h32,
                                              const unsigned short* __restrict__ wrel,
                                              const unsigned short* __restrict__ wroot,
                                              const float* __restrict__ bias,
                                              const float* __restrict__ gamma,
                                              const float* __restrict__ beta,
                                              float* __restrict__ out_f,
                                              int add_res, int last) {
    __shared__ char smraw[4 * 16 * PADF * 4];
    float* SLF = (float*)smraw;
    uint4* SB4 = (uint4*)smraw;
    const unsigned short* SBs = (const unsigned short*)smraw;

    int tid = threadIdx.x;
    int wave = tid >> 6, lane = tid & 63;
    int quad = lane >> 4, l15 = lane & 15;
    int w0 = blockIdx.x * 64 + wave * 16;
    int gi = w0 + l15; gi = gi < NN ? gi : NN - 1;
    float* WF = SLF + wave * 16 * PADF;

    float4v acc[8];
#pragma unroll
    for (int i = 0; i < 8; i++) acc[i] = (float4v){0.f, 0.f, 0.f, 0.f};

    const unsigned* Sr = S + (size_t)gi * 512;
    for (int r = 0; r < NR; r++) {
        short8 afr[4];
#pragma unroll
        for (int kk = 0; kk < 4; kk++)
            afr[kk] = *(const short8*)&Sr[r * 64 + kk * 16 + quad * 4];
        __syncthreads();
        {
            const uint4* Wg = (const uint4*)(wrel + (size_t)r * 16384);
#pragma unroll
            for (int i = 0; i < 8; i++) SB4[tid + 256 * i] = Wg[tid + 256 * i];
        }
        __syncthreads();
#pragma unroll
        for (int kk = 0; kk < 4; kk++) {
#pragma unroll
            for (int ft = 0; ft < 8; ft++) {
                short8 bf = *(const short8*)&SBs[((kk * 8 + ft) * 64 + lane) * 8];
                acc[ft] = __builtin_amdgcn_mfma_f32_16x16x32_bf16(afr[kk], bf, acc[ft], 0, 0, 0);
            }
        }
    }
    {
        const unsigned* Hr = h32 + (size_t)gi * 64;
        short8 afr[4];
#pragma unroll
        for (int kk = 0; kk < 4; kk++)
            afr[kk] = *(const short8*)&Hr[kk * 16 + quad * 4];
        __syncthreads();
        {
            const uint4* Wg = (const uint4*)wroot;
#pragma unroll
            for (int i = 0; i < 8; i++) SB4[tid + 256 * i] = Wg[tid + 256 * i];
        }
        __syncthreads();
#pragma unroll
        for (int kk = 0; kk < 4; kk++) {
#pragma unroll
            for (int ft = 0; ft < 8; ft++) {
                short8 bf = *(const short8*)&SBs[((kk * 8 + ft) * 64 + lane) * 8];
                acc[ft] = __builtin_amdgcn_mfma_f32_16x16x32_bf16(afr[kk], bf, acc[ft], 0, 0, 0);
            }
        }
    }
    __syncthreads();

#pragma unroll
    for (int ft = 0; ft < 8; ft++)
#pragma unroll
        for (int rg = 0; rg < 4; rg++)
            WF[(quad * 4 + rg) * PADF + ft * 16 + l15] = acc[ft][rg];

    float2 bia = *(const float2*)&bias[2 * lane];
    float2 gam = *(const float2*)&gamma[2 * lane];
    float2 bet = *(const float2*)&beta[2 * lane];

    for (int i = 0; i < 16; i++) {
        int g = w0 + i;
        if (g >= NN) continue;
        float v0 = WF[i * PADF + 2 * lane] + bia.x;
        float v1 = WF[i * PADF + 2 * lane + 1] + bia.y;
        float s = v0 + v1;
#pragma unroll
        for (int off = 32; off > 0; off >>= 1) s += __shfl_xor(s, off, 64);
        float mu = s * (1.0f / ND);
        float e0 = v0 - mu, e1 = v1 - mu;
        float vs = e0 * e0 + e1 * e1;
#pragma unroll
        for (int off = 32; off > 0; off >>= 1) vs += __shfl_xor(vs, off, 64);
        float rr = rsqrtf(vs * (1.0f / ND) + LN_EPS);
        float o0 = fmaxf(e0 * rr * gam.x + bet.x, 0.0f);
        float o1 = fmaxf(e1 * rr * gam.y + bet.y, 0.0f);
        if (add_res) {
            unsigned u = h32[(size_t)g * 64 + lane];
            o0 += bflo(u);
            o1 += bfhi(u);
        }
        if (last) {
            *(float2*)&out_f[(size_t)g * ND + 2 * lane] = make_float2(o0, o1);
        } else {
            h32[(size_t)g * 64 + lane] = pack2(o0, o1);
        }
    }
}

extern "C" void kernel_launch(void* const* d_in, const int* in_sizes, int n_in,
                              void* d_out, int out_size, void* d_ws, size_t ws_size,
                              hipStream_t stream) {
    const int*   x      = (const int*)d_in[0];
    const int*   ei     = (const int*)d_in[1];
    const int*   et     = (const int*)d_in[2];
    const float* emb    = (const float*)d_in[3];
    const float* w_rel  = (const float*)d_in[4];
    const float* w_root = (const float*)d_in[5];
    const float* bias   = (const float*)d_in[6];
    const float* gamma  = (const float*)d_in[7];
    const float* beta   = (const float*)d_in[8];
    float* out = (float*)d_out;

    char* ws = (char*)d_ws;
    unsigned* h        = (unsigned*)(ws + WS_H);     // 12.8 MB bf16x2 rows
    int*      rowstart = (int*)     (ws + WS_ROW);   // 1.6 MB + 4
    int*      bcur     = (int*)     (ws + WS_BCUR);  // 784 B (rowstart slack)
    int*      adj      = (int*)     (ws + WS_ADJ);   // 6.4 MB
    unsigned short* wb = (unsigned short*)(ws + WS_WB);  // 884736 B
    unsigned* big      = (unsigned*)(ws + WS_BIG);   // hr 115.2 MB | S 102.4 MB
    unsigned* stage    = (unsigned*)d_out;           // 8 MB in out (dead until last aggln)

    const int* src = ei;
    const int* dst = ei + NE;

    hipMemsetAsync(bcur, 0, NBKT * sizeof(int), stream);   // MUST precede binA atomics

    k_prepbin<<<BIN_BLOCKS + PREP_BLOCKS, 256, 0, stream>>>(
        x, emb, w_rel, w_root, src, dst, et, h, wb, bcur, stage);

    if (ws_size >= WS_NEED_NEW) {
        k_binB_mm<<<NBKT + MM_BLOCKS_FU, 256, 0, stream>>>(
            stage, bcur, rowstart, adj,
            h, wb, wb + (size_t)24 * 16384, big);
        k_aggln<<<NN / 4, 256, 0, stream>>>(
            big, h, adj, rowstart,
            bias, gamma, beta, out, 0, 0);
        for (int l = 1; l < NL; l++) {
            k_mm<<<MM_BLOCKS_SA, 256, 0, stream>>>(
                h, wb + (size_t)l * 8 * 16384, wb + (size_t)(24 + l) * 16384, big);
            k_aggln<<<NN / 4, 256, 0, stream>>>(
                big, h, adj, rowstart,
                bias + l * ND, gamma + l * ND, beta + l * ND,
                out, 1, l == NL - 1);
        }
    } else {
        k_binB<<<NBKT, 256, 0, stream>>>(stage, bcur, rowstart, adj);
        for (int l = 0; l < NL; l++) {
            k_agg<<<RN * 16 / 256, 256, 0, stream>>>(h, adj, rowstart, big);
            k_gemm<<<(NN + 63) / 64, 256, 0, stream>>>(
                big, h,
                wb + (size_t)l * 8 * 16384, wb + (size_t)(24 + l) * 16384,
                bias + l * ND, gamma + l * ND, beta + l * ND,
                out, l > 0, l == NL - 1);
        }
    }
}

// Round 11
// 499.168 us; speedup vs baseline: 1.1986x; 1.1986x over previous
//
#include <hip/hip_runtime.h>

#define NN 50000
#define NE 1600000
#define NR 8
#define ND 128
#define NL 3
#define RN (NR * NN)
#define LN_EPS 1e-5f
#define PADF 132   // f32 elems per epilogue scratch row (8448 B per wave region)

// binning
#define NBKT 196          // seg >> 11 -> 196 coarse buckets (2048 segs each)
#define BSH 11
#define STRIDE_PB 10240   // stage dwords per bucket (mean 8163, +23 sigma; verified r5/r6)
#define BIN_BLOCKS 1000   // 1600 edges each (r10: TLP win, keep)
#define EPB 1600          // edges per binA block
#define I4PB 400          // int4 loads per stream per block
#define MM_BLOCKS_SA ((NN + 127) / 128)      // 391 standalone (128 rows, NG=2)
#define MM_BLOCKS_FU ((NN + 63) / 64)        // 782 in fused launch (64 rows, NG=1)

// prep region sizes (bcur zeroed via hipMemsetAsync, NOT in-grid: r7 crash was
// binA blocks racing the prep block that zeroed bcur — block order is undefined)
#define PREP_G (NN * 64)        // gather dwords
#define PREP_W (27 * 16384)     // wprep elems
#define PREP_TOT (PREP_G + PREP_W)
#define PREP_BLOCKS ((PREP_TOT + 255) / 256)

// workspace layout
#define WS_H    0
#define WS_ROW  14400000
#define WS_BCUR 16000064     // 784 B in rowstart region slack (rowstart ends 16,000,004)
#define WS_ADJ  16004096
#define WS_WB   22404096
#define WS_BIG  23288832
#define WS_NEED_NEW (23288832ULL + 9ULL * NN * 256)   // hr = 9 tables -> 138.5 MB
// stage lives in d_out (25.6 MB, dead until the last aggln overwrites it fully)

typedef __attribute__((ext_vector_type(8))) short short8;
typedef __attribute__((ext_vector_type(4))) float float4v;
typedef __attribute__((ext_vector_type(4))) unsigned uint4v;

__device__ __forceinline__ float bflo(unsigned u) { return __uint_as_float(u << 16); }
__device__ __forceinline__ float bfhi(unsigned u) { return __uint_as_float(u & 0xFFFF0000u); }
__device__ __forceinline__ unsigned f2bf(float f) {
    unsigned u = __float_as_uint(f);
    return (u + 0x7FFFu + ((u >> 16) & 1u)) >> 16;   // RNE
}
__device__ __forceinline__ unsigned pack2(float lo, float hi) {
    return f2bf(lo) | (f2bf(hi) << 16);
}

// ---- launch 1: binA (blocks [0,1000)) || prep (h gather | wprep) ----
// bcur pre-zeroed on-stream (memset) so binA's atomicAdds are safe.
__global__ __launch_bounds__(256) void k_prepbin(const int* __restrict__ x,
                                                 const float* __restrict__ emb,
                                                 const float* __restrict__ w_rel,
                                                 const float* __restrict__ w_root,
                                                 const int* __restrict__ src,
                                                 const int* __restrict__ dst,
                                                 const int* __restrict__ et,
                                                 unsigned* __restrict__ h,
                                                 unsigned short* __restrict__ wb,
                                                 int* __restrict__ bcur,
                                                 unsigned* __restrict__ stage) {
    __shared__ int lcnt[256];
    __shared__ int loff[256];
    __shared__ int lcur[256];
    __shared__ int sbase[256];
    __shared__ int tmp[256];
    __shared__ unsigned srt[EPB];          // 6.4 KB
    __shared__ unsigned char bkt[EPB];     // 1.6 KB

    int tid = threadIdx.x;
    if (blockIdx.x >= BIN_BLOCKS) {
        // ---- prep path ----
        int i = (blockIdx.x - BIN_BLOCKS) * 256 + tid;
        if (i < PREP_G) {
            int n = i >> 6, dw = i & 63;
            float2 v = *(const float2*)&emb[(size_t)x[n] * ND + 2 * dw];
            h[i] = pack2(v.x, v.y);
            return;
        }
        i -= PREP_G;
        if (i < PREP_W) {
            int m = i >> 14;
            int idx = i & 16383;
            int j = idx & 7;
            int lane = (idx >> 3) & 63;
            int ft = (idx >> 9) & 7;
            int kk = idx >> 12;
            int row = kk * 32 + (lane >> 4) * 8 + j;
            int col = ft * 16 + (lane & 15);
            const float* W = (m < 24) ? (w_rel + (size_t)m * 16384)
                                      : (w_root + (size_t)(m - 24) * 16384);
            wb[i] = (unsigned short)f2bf(W[row * ND + col]);
        }
        return;
    }

    // ---- binA path: per-block LDS counting sort by coarse bucket ----
    lcnt[tid] = 0;
    __syncthreads();

    int base4 = blockIdx.x * I4PB;
    const int4* s4p = (const int4*)src;
    const int4* d4p = (const int4*)dst;
    const int4* t4p = (const int4*)et;

    for (int i4 = tid; i4 < I4PB; i4 += 256) {
        int4 d4 = d4p[base4 + i4];
        int4 t4 = t4p[base4 + i4];
        atomicAdd(&lcnt[(t4.x * NN + d4.x) >> BSH], 1);
        atomicAdd(&lcnt[(t4.y * NN + d4.y) >> BSH], 1);
        atomicAdd(&lcnt[(t4.z * NN + d4.z) >> BSH], 1);
        atomicAdd(&lcnt[(t4.w * NN + d4.w) >> BSH], 1);
    }
    __syncthreads();
    int own = lcnt[tid];
    tmp[tid] = own;
    __syncthreads();
    for (int off = 1; off < 256; off <<= 1) {
        int v = (tid >= off) ? tmp[tid - off] : 0;
        __syncthreads();
        tmp[tid] += v;
        __syncthreads();
    }
    int excl = tmp[tid] - own;
    loff[tid] = excl;
    lcur[tid] = excl;
    if (tid < NBKT) sbase[tid] = atomicAdd(&bcur[tid], own);
    __syncthreads();

    for (int i4 = tid; i4 < I4PB; i4 += 256) {
        int4 s4 = s4p[base4 + i4];
        int4 d4 = d4p[base4 + i4];
        int4 t4 = t4p[base4 + i4];
        int segs[4] = {t4.x * NN + d4.x, t4.y * NN + d4.y,
                       t4.z * NN + d4.z, t4.w * NN + d4.w};
        int srcs[4] = {s4.x, s4.y, s4.z, s4.w};
#pragma unroll
        for (int j = 0; j < 4; j++) {
            int seg = segs[j];
            int b = seg >> BSH;
            unsigned rec = ((unsigned)(seg & 2047) << 16) | (unsigned)srcs[j];
            int pos = atomicAdd(&lcur[b], 1);
            srt[pos] = rec;
            bkt[pos] = (unsigned char)b;
        }
    }
    __syncthreads();
    for (int i = tid; i < EPB; i += 256) {
        int b = bkt[i];
        int idx = sbase[b] + (i - loff[b]);
        if (idx < STRIDE_PB)                     // insurance: degrade, don't fault
            stage[(size_t)b * STRIDE_PB + idx] = srt[i];
    }
}

// ---- shared body for binB (used by fused launch 2 and the fallback) ----
__device__ __forceinline__ void binB_body(const unsigned* __restrict__ stage,
                                          const int* __restrict__ bcur,
                                          int* __restrict__ rowstart,
                                          int* __restrict__ adj,
                                          int b, int tid,
                                          int* tmp, int* lcnt2, int* loff2,
                                          unsigned short* srt2, int* misc) {
    // gbase = exclusive prefix of bucket totals at b
    int bv = (tid < NBKT) ? bcur[tid] : 0;
    tmp[tid] = bv;
    __syncthreads();
    for (int off = 1; off < 256; off <<= 1) {
        int v = (tid >= off) ? tmp[tid - off] : 0;
        __syncthreads();
        tmp[tid] += v;
        __syncthreads();
    }
    if (tid == b) { misc[0] = tmp[tid] - bv; misc[1] = bv; }
    for (int j = tid; j < 2048; j += 256) lcnt2[j] = 0;
    __syncthreads();

    int n = misc[1];
    n = n < STRIDE_PB ? n : STRIDE_PB;           // insurance
    const unsigned* sp = stage + (size_t)b * STRIDE_PB;
    for (int i = tid; i < n; i += 256)
        atomicAdd(&lcnt2[sp[i] >> 16], 1);
    __syncthreads();

    int v8[8];
    int s8 = 0;
    int base8 = tid * 8;
#pragma unroll
    for (int j = 0; j < 8; j++) { v8[j] = lcnt2[base8 + j]; s8 += v8[j]; }
    tmp[tid] = s8;
    __syncthreads();
    for (int off = 1; off < 256; off <<= 1) {
        int v = (tid >= off) ? tmp[tid - off] : 0;
        __syncthreads();
        tmp[tid] += v;
        __syncthreads();
    }
    int run = tmp[tid] - s8;
#pragma unroll
    for (int j = 0; j < 8; j++) { loff2[base8 + j] = run; run += v8[j]; }
    __syncthreads();
    for (int j = tid; j < 2048; j += 256) lcnt2[j] = loff2[j];
    __syncthreads();

    for (int i = tid; i < n; i += 256) {
        unsigned rec = sp[i];
        int pos = atomicAdd(&lcnt2[rec >> 16], 1);
        srt2[pos] = (unsigned short)(rec & 0xFFFFu);
    }
    __syncthreads();

    int gb = misc[0];
    for (int i = tid; i < n; i += 256) adj[gb + i] = (int)srt2[i];
    int segbase = b << BSH;
    for (int j = tid; j < 2048; j += 256) {
        int seg = segbase + j;
        if (seg < RN) rowstart[seg] = gb + loff2[j];
    }
    if (b == NBKT - 1 && tid == 0) rowstart[RN] = NE;
}

typedef unsigned TRarr[16][66];

// ---- shared body for k_mm, NG row-groups (64 rows each) per block.
// NG=2 standalone (halves B-stage L2 traffic, amortizes barriers); NG=1 in
// the fused launch (978 short blocks pack better with binB — r9 showed 391
// long blocks drop fused occupancy to 13%). TR scratch time-shared
// (wave-private, DS ops complete in issue order -> no barrier).
template <int NG>
__device__ __forceinline__ void mm_body(const unsigned* __restrict__ h32,
                                        const unsigned short* __restrict__ wrel,
                                        const unsigned short* __restrict__ wroot,
                                        unsigned* __restrict__ hr,
                                        int mb, int tid,
                                        uint4* SB4, TRarr* TRp) {
    const unsigned short* SBs = (const unsigned short*)SB4;
    int wave = tid >> 6, lane = tid & 63;
    int quad = lane >> 4, l15 = lane & 15;
    int pr = l15 & 1;

    int rbase[NG];
    short8 af[NG][4];
#pragma unroll
    for (int g = 0; g < NG; g++) {
        rbase[g] = mb * (64 * NG) + g * 64 + wave * 16;
        int gi = rbase[g] + l15; gi = gi < NN ? gi : NN - 1;
        const unsigned* H = h32 + (size_t)gi * 64;
#pragma unroll
        for (int kk = 0; kk < 4; kk++)
            af[g][kk] = *(const short8*)&H[kk * 16 + quad * 4];
    }

    for (int m = 0; m < 9; m++) {
        const unsigned short* W = (m < 8) ? (wrel + (size_t)m * 16384) : wroot;
        __syncthreads();
        {
            const uint4* Wg = (const uint4*)W;
#pragma unroll
            for (int i = 0; i < 8; i++) SB4[tid + 256 * i] = Wg[tid + 256 * i];
        }
        __syncthreads();

        float4v ac[NG][8];
#pragma unroll
        for (int g = 0; g < NG; g++)
#pragma unroll
            for (int i = 0; i < 8; i++) ac[g][i] = (float4v){0.f, 0.f, 0.f, 0.f};
#pragma unroll
        for (int kk = 0; kk < 4; kk++) {
#pragma unroll
            for (int ft = 0; ft < 8; ft++) {
                short8 bf = *(const short8*)&SBs[((kk * 8 + ft) * 64 + lane) * 8];
#pragma unroll
                for (int g = 0; g < NG; g++)
                    ac[g][ft] = __builtin_amdgcn_mfma_f32_16x16x32_bf16(af[g][kk], bf, ac[g][ft], 0, 0, 0);
            }
        }

        unsigned* hrm = hr + (size_t)m * NN * 64;
#pragma unroll
        for (int g = 0; g < NG; g++) {
            // pack + wave-private transpose (no barrier: same-wave order)
#pragma unroll
            for (int ft = 0; ft < 8; ft++) {
                float4v part;
#pragma unroll
                for (int rg = 0; rg < 4; rg++) part[rg] = __shfl_xor(ac[g][ft][rg], 1, 64);
                if ((ft & 1) == pr) {
                    int a = l15 >> 1;
#pragma unroll
                    for (int rg = 0; rg < 4; rg++) {
                        float lo = pr ? part[rg] : ac[g][ft][rg];
                        float hi = pr ? ac[g][ft][rg] : part[rg];
                        TRp[wave][quad * 4 + rg][ft * 8 + a] = pack2(lo, hi);
                    }
                }
            }
#pragma unroll
            for (int ps = 0; ps < 4; ps++) {
                int ri = ps * 4 + quad;
                uint4 v = *(const uint4*)&TRp[wave][ri][l15 * 4];
                int row = rbase[g] + ri;
                if (row < NN)
                    *(uint4*)&hrm[(size_t)row * 64 + l15 * 4] = v;
            }
        }
    }
}

// ---- launch 2: binB (blocks [0,196)) || mm layer 0 (blocks [196, 196+782), NG=1) ----
// stage lives in d_out so mm's hr writes (big) cannot race binB's stage reads.
__global__ __launch_bounds__(256) void k_binB_mm(const unsigned* __restrict__ stage,
                                                 const int* __restrict__ bcur,
                                                 int* __restrict__ rowstart,
                                                 int* __restrict__ adj,
                                                 const unsigned* __restrict__ h32,
                                                 const unsigned short* __restrict__ wrel,
                                                 const unsigned short* __restrict__ wroot,
                                                 unsigned* __restrict__ hr) {
    __shared__ uint4 SMEM[3104];   // 49664 B union: binB 37.9 KB | mm 48.5 KB
    int tid = threadIdx.x;
    if (blockIdx.x < NBKT) {
        int* tmp = (int*)SMEM;
        int* lcnt2 = (int*)SMEM + 256;
        int* loff2 = (int*)SMEM + 2304;
        unsigned short* srt2 = (unsigned short*)((int*)SMEM + 4352);
        int* misc = (int*)SMEM + 9472;
        binB_body(stage, bcur, rowstart, adj, blockIdx.x, tid,
                  tmp, lcnt2, loff2, srt2, misc);
    } else {
        mm_body<1>(h32, wrel, wroot, hr, blockIdx.x - NBKT, tid,
                   SMEM, (TRarr*)(SMEM + 2048));
    }
}

// standalone kernels for layers 1,2 (and fallback)
__global__ __launch_bounds__(256) void k_binB(const unsigned* __restrict__ stage,
                                              const int* __restrict__ bcur,
                                              int* __restrict__ rowstart,
                                              int* __restrict__ adj) {
    __shared__ uint4 SMEM[2369];   // 37904 B
    int tid = threadIdx.x;
    int* tmp = (int*)SMEM;
    int* lcnt2 = (int*)SMEM + 256;
    int* loff2 = (int*)SMEM + 2304;
    unsigned short* srt2 = (unsigned short*)((int*)SMEM + 4352);
    int* misc = (int*)SMEM + 9472;
    binB_body(stage, bcur, rowstart, adj, blockIdx.x, tid,
              tmp, lcnt2, loff2, srt2, misc);
}

__global__ __launch_bounds__(256) void k_mm(const unsigned* __restrict__ h32,
                                            const unsigned short* __restrict__ wrel,
                                            const unsigned short* __restrict__ wroot,
                                            unsigned* __restrict__ hr) {
    __shared__ uint4 SMEM[3104];
    mm_body<2>(h32, wrel, wroot, hr, blockIdx.x, threadIdx.x,
               SMEM, (TRarr*)(SMEM + 2048));
}

#define AGA(u)                                  \
    a0 += bflo(u.x); a1 += bfhi(u.x);           \
    a2 += bflo(u.y); a3 += bfhi(u.y);           \
    a4 += bflo(u.z); a5 += bfhi(u.z);           \
    a6 += bflo(u.w); a7 += bfhi(u.w);
#define AGC(u)                                  \
    c0 += bflo(u.x); c1 += bfhi(u.x);           \
    c2 += bflo(u.y); c3 += bfhi(u.y);           \
    c4 += bflo(u.z); c5 += bfhi(u.z);           \
    c6 += bflo(u.w); c7 += bfhi(u.w);

// aggln (r8-proven form, reverted from r10's wave-per-node regression):
// 16-lane quad per node, uint4 (16B) per lane per edge row. One wave-wide
// load inst = 4 quads x 256B = 1KB across 4 rows; r10's 1-dword-per-lane
// variant fetched only 256B/inst and ran 54% slower — the kernel is
// load-WIDTH-bound, not divergence-bound. Clamps dropped (adj < NN by
// construction); 4/2/1 edge loop (deg ~ Poisson(4)).
__global__ __launch_bounds__(256) void k_aggln(const unsigned* __restrict__ hr,
                                               unsigned* __restrict__ h32,
                                               const int* __restrict__ adj,
                                               const int* __restrict__ rowstart,
                                               const float* __restrict__ bias,
                                               const float* __restrict__ gamma,
                                               const float* __restrict__ beta,
                                               float* __restrict__ out_f,
                                               int add_res, int last) {
    int n = (blockIdx.x * 256 + threadIdx.x) >> 4;   // grid exact: 3125*256/16
    int l15 = threadIdx.x & 15;

    float t0 = 0.f, t1 = 0.f, t2 = 0.f, t3 = 0.f,
          t4 = 0.f, t5 = 0.f, t6 = 0.f, t7 = 0.f;

    for (int r = 0; r < NR; r++) {
        int seg = r * NN + n;
        int st = rowstart[seg], en = rowstart[seg + 1];
        st = st < 0 ? 0 : st;
        en = en > NE ? NE : en;
        const unsigned* T = hr + (size_t)r * NN * 64;

        float a0 = 0.f, a1 = 0.f, a2 = 0.f, a3 = 0.f,
              a4 = 0.f, a5 = 0.f, a6 = 0.f, a7 = 0.f;
        float c0 = 0.f, c1 = 0.f, c2 = 0.f, c3 = 0.f,
              c4 = 0.f, c5 = 0.f, c6 = 0.f, c7 = 0.f;
        int p = st;
        for (; p + 3 < en; p += 4) {
            unsigned s0 = (unsigned)adj[p],     s1 = (unsigned)adj[p + 1];
            unsigned s2 = (unsigned)adj[p + 2], s3 = (unsigned)adj[p + 3];
            uint4 u0 = *(const uint4*)&T[(size_t)s0 * 64 + l15 * 4];
            uint4 u1 = *(const uint4*)&T[(size_t)s1 * 64 + l15 * 4];
            uint4 u2 = *(const uint4*)&T[(size_t)s2 * 64 + l15 * 4];
            uint4 u3 = *(const uint4*)&T[(size_t)s3 * 64 + l15 * 4];
            AGA(u0) AGC(u1) AGA(u2) AGC(u3)
        }
        for (; p + 1 < en; p += 2) {
            unsigned s0 = (unsigned)adj[p], s1 = (unsigned)adj[p + 1];
            uint4 u0 = *(const uint4*)&T[(size_t)s0 * 64 + l15 * 4];
            uint4 u1 = *(const uint4*)&T[(size_t)s1 * 64 + l15 * 4];
            AGA(u0) AGC(u1)
        }
        if (p < en) {
            unsigned s0 = (unsigned)adj[p];
            uint4 u0 = *(const uint4*)&T[(size_t)s0 * 64 + l15 * 4];
            AGA(u0)
        }
        int d = en - st;
        float sc = 1.0f / (float)(d > 1 ? d : 1);
        t0 += (a0 + c0) * sc; t1 += (a1 + c1) * sc;
        t2 += (a2 + c2) * sc; t3 += (a3 + c3) * sc;
        t4 += (a4 + c4) * sc; t5 += (a5 + c5) * sc;
        t6 += (a6 + c6) * sc; t7 += (a7 + c7) * sc;
    }

    // root row + bias
    {
        uint4 u = *(const uint4*)&hr[((size_t)8 * NN + n) * 64 + l15 * 4];
        t0 += bflo(u.x); t1 += bfhi(u.x);
        t2 += bflo(u.y); t3 += bfhi(u.y);
        t4 += bflo(u.z); t5 += bfhi(u.z);
        t6 += bflo(u.w); t7 += bfhi(u.w);
    }
    int f0 = 8 * l15;
    {
        float4 b0 = *(const float4*)&bias[f0];
        float4 b1 = *(const float4*)&bias[f0 + 4];
        t0 += b0.x; t1 += b0.y; t2 += b0.z; t3 += b0.w;
        t4 += b1.x; t5 += b1.y; t6 += b1.z; t7 += b1.w;
    }

    float s = t0 + t1 + t2 + t3 + t4 + t5 + t6 + t7;
#pragma unroll
    for (int off = 1; off < 16; off <<= 1) s += __shfl_xor(s, off, 64);
    float mu = s * (1.0f / ND);
    float e0 = t0 - mu, e1 = t1 - mu, e2 = t2 - mu, e3 = t3 - mu,
          e4 = t4 - mu, e5 = t5 - mu, e6 = t6 - mu, e7 = t7 - mu;
    float vs = e0 * e0 + e1 * e1 + e2 * e2 + e3 * e3 +
               e4 * e4 + e5 * e5 + e6 * e6 + e7 * e7;
#pragma unroll
    for (int off = 1; off < 16; off <<= 1) vs += __shfl_xor(vs, off, 64);
    float rr = rsqrtf(vs * (1.0f / ND) + LN_EPS);

    float4 g0 = *(const float4*)&gamma[f0];
    float4 g1 = *(const float4*)&gamma[f0 + 4];
    float4 be0 = *(const float4*)&beta[f0];
    float4 be1 = *(const float4*)&beta[f0 + 4];
    float o0 = fmaxf(e0 * rr * g0.x + be0.x, 0.0f);
    float o1 = fmaxf(e1 * rr * g0.y + be0.y, 0.0f);
    float o2 = fmaxf(e2 * rr * g0.z + be0.z, 0.0f);
    float o3 = fmaxf(e3 * rr * g0.w + be0.w, 0.0f);
    float o4 = fmaxf(e4 * rr * g1.x + be1.x, 0.0f);
    float o5 = fmaxf(e5 * rr * g1.y + be1.y, 0.0f);
    float o6 = fmaxf(e6 * rr * g1.z + be1.z, 0.0f);
    float o7 = fmaxf(e7 * rr * g1.w + be1.w, 0.0f);

    if (add_res) {
        uint4 u = *(const uint4*)&h32[(size_t)n * 64 + l15 * 4];
        o0 += bflo(u.x); o1 += bfhi(u.x);
        o2 += bflo(u.y); o3 += bfhi(u.y);
        o4 += bflo(u.z); o5 += bfhi(u.z);
        o6 += bflo(u.w); o7 += bfhi(u.w);
    }
    if (last) {
        *(float4*)&out_f[(size_t)n * ND + f0] = make_float4(o0, o1, o2, o3);
        *(float4*)&out_f[(size_t)n * ND + f0 + 4] = make_float4(o4, o5, o6, o7);
    } else {
        uint4 w;
        w.x = pack2(o0, o1); w.y = pack2(o2, o3);
        w.z = pack2(o4, o5); w.w = pack2(o6, o7);
        *(uint4*)&h32[(size_t)n * 64 + l15 * 4] = w;
    }
}

// ---------- FALLBACK PATH (ws too small): proven round-2 agg+gemm ----------

__global__ __launch_bounds__(256) void k_agg(const unsigned* __restrict__ h32,
                                             const int* __restrict__ adj,
                                             const int* __restrict__ rowstart,
                                             unsigned* __restrict__ S) {
    int q = (blockIdx.x * 256 + threadIdx.x) >> 4;
    int l15 = threadIdx.x & 15;
    int r = q / NN;
    int n = q - r * NN;
    int st = rowstart[q], en = rowstart[q + 1];
    st = st < 0 ? 0 : st;
    en = en > NE ? NE : en;
    float a0 = 0.f, a1 = 0.f, a2 = 0.f, a3 = 0.f,
          a4 = 0.f, a5 = 0.f, a6 = 0.f, a7 = 0.f;
    float c0 = 0.f, c1 = 0.f, c2 = 0.f, c3 = 0.f,
          c4 = 0.f, c5 = 0.f, c6 = 0.f, c7 = 0.f;
    int p = st;
    for (; p + 3 < en; p += 4) {
        unsigned s0 = (unsigned)adj[p],     s1 = (unsigned)adj[p + 1];
        unsigned s2 = (unsigned)adj[p + 2], s3 = (unsigned)adj[p + 3];
        uint4 u0 = *(const uint4*)&h32[(size_t)s0 * 64 + l15 * 4];
        uint4 u1 = *(const uint4*)&h32[(size_t)s1 * 64 + l15 * 4];
        uint4 u2 = *(const uint4*)&h32[(size_t)s2 * 64 + l15 * 4];
        uint4 u3 = *(const uint4*)&h32[(size_t)s3 * 64 + l15 * 4];
        AGA(u0) AGC(u1) AGA(u2) AGC(u3)
    }
    for (; p < en; p++) {
        unsigned s0 = (unsigned)adj[p];
        uint4 u0 = *(const uint4*)&h32[(size_t)s0 * 64 + l15 * 4];
        AGA(u0)
    }
    int d = en - st;
    float sc = 1.0f / (float)(d > 1 ? d : 1);
    a0 = (a0 + c0) * sc; a1 = (a1 + c1) * sc;
    a2 = (a2 + c2) * sc; a3 = (a3 + c3) * sc;
    a4 = (a4 + c4) * sc; a5 = (a5 + c5) * sc;
    a6 = (a6 + c6) * sc; a7 = (a7 + c7) * sc;
    uint4v w;
    w.x = pack2(a0, a1); w.y = pack2(a2, a3);
    w.z = pack2(a4, a5); w.w = pack2(a6, a7);
    __builtin_nontemporal_store(w, (uint4v*)&S[(size_t)n * 512 + r * 64 + l15 * 4]);
}

__global__ __launch_bounds__(256) void k_gemm(const unsigned* __restrict__ S,
                                              unsigned* __restrict__ h32,
                                              const unsigned short* __restrict__ wrel,
                                              const unsigned short* __restrict__ wroot,
                                              const float* __restrict__ bias,
                                              const float* __restrict__ gamma,
                                              const float* __restrict__ beta,
                                              float* __restrict__ out_f,
                                              int add_res, int last) {
    __shared__ char smraw[4 * 16 * PADF * 4];
    float* SLF = (float*)smraw;
    uint4* SB4 = (uint4*)smraw;
    const unsigned short* SBs = (const unsigned short*)smraw;

    int tid = threadIdx.x;
    int wave = tid >> 6, lane = tid & 63;
    int quad = lane >> 4, l15 = lane & 15;
    int w0 = blockIdx.x * 64 + wave * 16;
    int gi = w0 + l15; gi = gi < NN ? gi : NN - 1;
    float* WF = SLF + wave * 16 * PADF;

    float4v acc[8];
#pragma unroll
    for (int i = 0; i < 8; i++) acc[i] = (float4v){0.f, 0.f, 0.f, 0.f};

    const unsigned* Sr = S + (size_t)gi * 512;
    for (int r = 0; r < NR; r++) {
        short8 afr[4];
#pragma unroll
        for (int kk = 0; kk < 4; kk++)
            afr[kk] = *(const short8*)&Sr[r * 64 + kk * 16 + quad * 4];
        __syncthreads();
        {
            const uint4* Wg = (const uint4*)(wrel + (size_t)r * 16384);
#pragma unroll
            for (int i = 0; i < 8; i++) SB4[tid + 256 * i] = Wg[tid + 256 * i];
        }
        __syncthreads();
#pragma unroll
        for (int kk = 0; kk < 4; kk++) {
#pragma unroll
            for (int ft = 0; ft < 8; ft++) {
                short8 bf = *(const short8*)&SBs[((kk * 8 + ft) * 64 + lane) * 8];
                acc[ft] = __builtin_amdgcn_mfma_f32_16x16x32_bf16(afr[kk], bf, acc[ft], 0, 0, 0);
            }
        }
    }
    {
        const unsigned* Hr = h32 + (size_t)gi * 64;
        short8 afr[4];
#pragma unroll
        for (int kk = 0; kk < 4; kk++)
            afr[kk] = *(const short8*)&Hr[kk * 16 + quad * 4];
        __syncthreads();
        {
            const uint4* Wg = (const uint4*)wroot;
#pragma unroll
            for (int i = 0; i < 8; i++) SB4[tid + 256 * i] = Wg[tid + 256 * i];
        }
        __syncthreads();
#pragma unroll
        for (int kk = 0; kk < 4; kk++) {
#pragma unroll
            for (int ft = 0; ft < 8; ft++) {
                short8 bf = *(const short8*)&SBs[((kk * 8 + ft) * 64 + lane) * 8];
                acc[ft] = __builtin_amdgcn_mfma_f32_16x16x32_bf16(afr[kk], bf, acc[ft], 0, 0, 0);
            }
        }
    }
    __syncthreads();

#pragma unroll
    for (int ft = 0; ft < 8; ft++)
#pragma unroll
        for (int rg = 0; rg < 4; rg++)
            WF[(quad * 4 + rg) * PADF + ft * 16 + l15] = acc[ft][rg];

    float2 bia = *(const float2*)&bias[2 * lane];
    float2 gam = *(const float2*)&gamma[2 * lane];
    float2 bet = *(const float2*)&beta[2 * lane];

    for (int i = 0; i < 16; i++) {
        int g = w0 + i;
        if (g >= NN) continue;
        float v0 = WF[i * PADF + 2 * lane] + bia.x;
        float v1 = WF[i * PADF + 2 * lane + 1] + bia.y;
        float s = v0 + v1;
#pragma unroll
        for (int off = 32; off > 0; off >>= 1) s += __shfl_xor(s, off, 64);
        float mu = s * (1.0f / ND);
        float e0 = v0 - mu, e1 = v1 - mu;
        float vs = e0 * e0 + e1 * e1;
#pragma unroll
        for (int off = 32; off > 0; off >>= 1) vs += __shfl_xor(vs, off, 64);
        float rr = rsqrtf(vs * (1.0f / ND) + LN_EPS);
        float o0 = fmaxf(e0 * rr * gam.x + bet.x, 0.0f);
        float o1 = fmaxf(e1 * rr * gam.y + bet.y, 0.0f);
        if (add_res) {
            unsigned u = h32[(size_t)g * 64 + lane];
            o0 += bflo(u);
            o1 += bfhi(u);
        }
        if (last) {
            *(float2*)&out_f[(size_t)g * ND + 2 * lane] = make_float2(o0, o1);
        } else {
            h32[(size_t)g * 64 + lane] = pack2(o0, o1);
        }
    }
}

extern "C" void kernel_launch(void* const* d_in, const int* in_sizes, int n_in,
                              void* d_out, int out_size, void* d_ws, size_t ws_size,
                              hipStream_t stream) {
    const int*   x      = (const int*)d_in[0];
    const int*   ei     = (const int*)d_in[1];
    const int*   et     = (const int*)d_in[2];
    const float* emb    = (const float*)d_in[3];
    const float* w_rel  = (const float*)d_in[4];
    const float* w_root = (const float*)d_in[5];
    const float* bias   = (const float*)d_in[6];
    const float* gamma  = (const float*)d_in[7];
    const float* beta   = (const float*)d_in[8];
    float* out = (float*)d_out;

    char* ws = (char*)d_ws;
    unsigned* h        = (unsigned*)(ws + WS_H);     // 12.8 MB bf16x2 rows
    int*      rowstart = (int*)     (ws + WS_ROW);   // 1.6 MB + 4
    int*      bcur     = (int*)     (ws + WS_BCUR);  // 784 B (rowstart slack)
    int*      adj      = (int*)     (ws + WS_ADJ);   // 6.4 MB
    unsigned short* wb = (unsigned short*)(ws + WS_WB);  // 884736 B
    unsigned* big      = (unsigned*)(ws + WS_BIG);   // hr 115.2 MB | S 102.4 MB
    unsigned* stage    = (unsigned*)d_out;           // 8 MB in out (dead until last aggln)

    const int* src = ei;
    const int* dst = ei + NE;

    hipMemsetAsync(bcur, 0, NBKT * sizeof(int), stream);   // MUST precede binA atomics

    k_prepbin<<<BIN_BLOCKS + PREP_BLOCKS, 256, 0, stream>>>(
        x, emb, w_rel, w_root, src, dst, et, h, wb, bcur, stage);

    if (ws_size >= WS_NEED_NEW) {
        k_binB_mm<<<NBKT + MM_BLOCKS_FU, 256, 0, stream>>>(
            stage, bcur, rowstart, adj,
            h, wb, wb + (size_t)24 * 16384, big);
        k_aggln<<<NN * 16 / 256, 256, 0, stream>>>(
            big, h, adj, rowstart,
            bias, gamma, beta, out, 0, 0);
        for (int l = 1; l < NL; l++) {
            k_mm<<<MM_BLOCKS_SA, 256, 0, stream>>>(
                h, wb + (size_t)l * 8 * 16384, wb + (size_t)(24 + l) * 16384, big);
            k_aggln<<<NN * 16 / 256, 256, 0, stream>>>(
                big, h, adj, rowstart,
                bias + l * ND, gamma + l * ND, beta + l * ND,
                out, 1, l == NL - 1);
        }
    } else {
        k_binB<<<NBKT, 256, 0, stream>>>(stage, bcur, rowstart, adj);
        for (int l = 0; l < NL; l++) {
            k_agg<<<RN * 16 / 256, 256, 0, stream>>>(h, adj, rowstart, big);
            k_gemm<<<(NN + 63) / 64, 256, 0, stream>>>(
                big, h,
                wb + (size_t)l * 8 * 16384, wb + (size_t)(24 + l) * 16384,
                bias + l * ND, gamma + l * ND, beta + l * ND,
                out, l > 0, l == NL - 1);
        }
    }
}

// Round 12
// 497.756 us; speedup vs baseline: 1.2020x; 1.0028x over previous
//
#include <hip/hip_runtime.h>

#define NN 50000
#define NE 1600000
#define NR 8
#define ND 128
#define NL 3
#define RN (NR * NN)
#define LN_EPS 1e-5f

// binning: key = dst*8 + et  (node-major!), bucket = key>>11
#define NBKT 196          // ceil(400000/2048)
#define BSH 11
#define STRIDE_PB 10240   // stage dwords per bucket (mean 8163, +23 sigma)
#define BIN_BLOCKS 1000   // 1600 edges each
#define EPB 1600
#define I4PB 400
#define MM_BLOCKS_SA ((NN + 127) / 128)      // 391 standalone (NG=2)
#define MM_BLOCKS_FU ((NN + 63) / 64)        // 782 fused (NG=1)

#define PREP_G (NN * 64)
#define PREP_W (27 * 16384)
#define PREP_TOT (PREP_G + PREP_W)
#define PREP_BLOCKS ((PREP_TOT + 255) / 256)

// workspace layout
#define WS_H    0
#define WS_NS   14400000     // nodestart: (NN+1) ints
#define WS_BCUR 16000064
#define WS_ADJ  16004096     // 6.4 MB (packed recs)
#define WS_WB   22404096
#define WS_BIG  23288832     // hr: 9 tables = 115.2 MB
// stage lives in d_out (25.6 MB, dead until last aggln overwrites it)

typedef __attribute__((ext_vector_type(8))) short short8;
typedef __attribute__((ext_vector_type(4))) float float4v;

__device__ __forceinline__ float bflo(unsigned u) { return __uint_as_float(u << 16); }
__device__ __forceinline__ float bfhi(unsigned u) { return __uint_as_float(u & 0xFFFF0000u); }
__device__ __forceinline__ unsigned f2bf(float f) {
    unsigned u = __float_as_uint(f);
    return (u + 0x7FFFu + ((u >> 16) & 1u)) >> 16;   // RNE
}
__device__ __forceinline__ unsigned pack2(float lo, float hi) {
    return f2bf(lo) | (f2bf(hi) << 16);
}

// ---- launch 1: binA (blocks [0,1000)) || prep (h gather | wprep) ----
// bcur pre-zeroed on-stream (memset) so binA's atomicAdds are safe (r7 lesson:
// never zero in-grid — block order undefined).
__global__ __launch_bounds__(256) void k_prepbin(const int* __restrict__ x,
                                                 const float* __restrict__ emb,
                                                 const float* __restrict__ w_rel,
                                                 const float* __restrict__ w_root,
                                                 const int* __restrict__ src,
                                                 const int* __restrict__ dst,
                                                 const int* __restrict__ et,
                                                 unsigned* __restrict__ h,
                                                 unsigned short* __restrict__ wb,
                                                 int* __restrict__ bcur,
                                                 unsigned* __restrict__ stage) {
    __shared__ int lcnt[256];
    __shared__ int loff[256];
    __shared__ int lcur[256];
    __shared__ int sbase[256];
    __shared__ int tmp[256];
    __shared__ unsigned srt[EPB];          // 6.4 KB
    __shared__ unsigned char bkt[EPB];     // 1.6 KB

    int tid = threadIdx.x;
    if (blockIdx.x >= BIN_BLOCKS) {
        int i = (blockIdx.x - BIN_BLOCKS) * 256 + tid;
        if (i < PREP_G) {
            int n = i >> 6, dw = i & 63;
            float2 v = *(const float2*)&emb[(size_t)x[n] * ND + 2 * dw];
            h[i] = pack2(v.x, v.y);
            return;
        }
        i -= PREP_G;
        if (i < PREP_W) {
            int m = i >> 14;
            int idx = i & 16383;
            int j = idx & 7;
            int lane = (idx >> 3) & 63;
            int ft = (idx >> 9) & 7;
            int kk = idx >> 12;
            int row = kk * 32 + (lane >> 4) * 8 + j;
            int col = ft * 16 + (lane & 15);
            const float* W = (m < 24) ? (w_rel + (size_t)m * 16384)
                                      : (w_root + (size_t)(m - 24) * 16384);
            wb[i] = (unsigned short)f2bf(W[row * ND + col]);
        }
        return;
    }

    // ---- binA: LDS counting sort by coarse bucket of key = dst*8+et ----
    lcnt[tid] = 0;
    __syncthreads();

    int base4 = blockIdx.x * I4PB;
    const int4* s4p = (const int4*)src;
    const int4* d4p = (const int4*)dst;
    const int4* t4p = (const int4*)et;

    for (int i4 = tid; i4 < I4PB; i4 += 256) {
        int4 d4 = d4p[base4 + i4];
        int4 t4 = t4p[base4 + i4];
        atomicAdd(&lcnt[(d4.x * 8 + t4.x) >> BSH], 1);
        atomicAdd(&lcnt[(d4.y * 8 + t4.y) >> BSH], 1);
        atomicAdd(&lcnt[(d4.z * 8 + t4.z) >> BSH], 1);
        atomicAdd(&lcnt[(d4.w * 8 + t4.w) >> BSH], 1);
    }
    __syncthreads();
    int own = lcnt[tid];
    tmp[tid] = own;
    __syncthreads();
    for (int off = 1; off < 256; off <<= 1) {
        int v = (tid >= off) ? tmp[tid - off] : 0;
        __syncthreads();
        tmp[tid] += v;
        __syncthreads();
    }
    int excl = tmp[tid] - own;
    loff[tid] = excl;
    lcur[tid] = excl;
    if (tid < NBKT) sbase[tid] = atomicAdd(&bcur[tid], own);
    __syncthreads();

    for (int i4 = tid; i4 < I4PB; i4 += 256) {
        int4 s4 = s4p[base4 + i4];
        int4 d4 = d4p[base4 + i4];
        int4 t4 = t4p[base4 + i4];
        int keys[4] = {d4.x * 8 + t4.x, d4.y * 8 + t4.y,
                       d4.z * 8 + t4.z, d4.w * 8 + t4.w};
        int srcs[4] = {s4.x, s4.y, s4.z, s4.w};
#pragma unroll
        for (int j = 0; j < 4; j++) {
            int key = keys[j];
            int b = key >> BSH;
            unsigned rec = ((unsigned)(key & 2047) << 16) | (unsigned)srcs[j];
            int pos = atomicAdd(&lcur[b], 1);
            srt[pos] = rec;
            bkt[pos] = (unsigned char)b;
        }
    }
    __syncthreads();
    for (int i = tid; i < EPB; i += 256) {
        int b = bkt[i];
        int idx = sbase[b] + (i - loff[b]);
        if (idx < STRIDE_PB)                     // insurance: degrade, don't fault
            stage[(size_t)b * STRIDE_PB + idx] = srt[i];
    }
}

// ---- binB: counting sort of bucket's 2048 keys; emits self-describing adj
// recs (r<<28 | deg<<16 | src) and compact nodestart[n] (key%8==0 prefixes).
__device__ __forceinline__ void binB_body(const unsigned* __restrict__ stage,
                                          const int* __restrict__ bcur,
                                          int* __restrict__ nodestart,
                                          unsigned* __restrict__ adj,
                                          int b, int tid,
                                          int* tmp, int* lcnt2, int* loff2,
                                          unsigned short* srt2, int* misc) {
    int bv = (tid < NBKT) ? bcur[tid] : 0;
    tmp[tid] = bv;
    __syncthreads();
    for (int off = 1; off < 256; off <<= 1) {
        int v = (tid >= off) ? tmp[tid - off] : 0;
        __syncthreads();
        tmp[tid] += v;
        __syncthreads();
    }
    if (tid == b) { misc[0] = tmp[tid] - bv; misc[1] = bv; }
    for (int j = tid; j < 2048; j += 256) lcnt2[j] = 0;
    __syncthreads();

    int n = misc[1];
    n = n < STRIDE_PB ? n : STRIDE_PB;           // insurance
    const unsigned* sp = stage + (size_t)b * STRIDE_PB;
    for (int i = tid; i < n; i += 256)
        atomicAdd(&lcnt2[sp[i] >> 16], 1);
    __syncthreads();

    int v8[8];
    int s8 = 0;
    int base8 = tid * 8;
#pragma unroll
    for (int j = 0; j < 8; j++) { v8[j] = lcnt2[base8 + j]; s8 += v8[j]; }
    tmp[tid] = s8;
    __syncthreads();
    for (int off = 1; off < 256; off <<= 1) {
        int v = (tid >= off) ? tmp[tid - off] : 0;
        __syncthreads();
        tmp[tid] += v;
        __syncthreads();
    }
    int run = tmp[tid] - s8;
#pragma unroll
    for (int j = 0; j < 8; j++) { loff2[base8 + j] = run; run += v8[j]; }
    __syncthreads();
    for (int j = tid; j < 2048; j += 256) lcnt2[j] = loff2[j];   // cursor
    __syncthreads();

    for (int i = tid; i < n; i += 256) {
        unsigned rec = sp[i];
        int pos = atomicAdd(&lcnt2[rec >> 16], 1);
        srt2[pos] = (unsigned short)(rec & 0xFFFFu);
    }
    __syncthreads();

    int gb = misc[0];
    int segbase = b << BSH;
#pragma unroll
    for (int jj = 0; jj < 8; jj++) {
        int j = base8 + jj;
        int key = segbase + j;
        if (key >= RN) break;
        int s = loff2[j], e = lcnt2[j];
        int d = e - s; d = d > 4095 ? 4095 : d;
        unsigned tag = ((unsigned)(key & 7) << 28) | ((unsigned)d << 16);
        for (int i = s; i < e; i++) adj[gb + i] = tag | (unsigned)srt2[i];
        if ((key & 7) == 0) nodestart[key >> 3] = gb + s;
    }
    if (b == NBKT - 1 && tid == 0) nodestart[NN] = NE;
}

typedef unsigned TRarr[16][66];

// ---- mm: NG row-groups (64 rows) per block. NG=2 standalone, NG=1 fused.
template <int NG>
__device__ __forceinline__ void mm_body(const unsigned* __restrict__ h32,
                                        const unsigned short* __restrict__ wrel,
                                        const unsigned short* __restrict__ wroot,
                                        unsigned* __restrict__ hr,
                                        int mb, int tid,
                                        uint4* SB4, TRarr* TRp) {
    const unsigned short* SBs = (const unsigned short*)SB4;
    int wave = tid >> 6, lane = tid & 63;
    int quad = lane >> 4, l15 = lane & 15;
    int pr = l15 & 1;

    int rbase[NG];
    short8 af[NG][4];
#pragma unroll
    for (int g = 0; g < NG; g++) {
        rbase[g] = mb * (64 * NG) + g * 64 + wave * 16;
        int gi = rbase[g] + l15; gi = gi < NN ? gi : NN - 1;
        const unsigned* H = h32 + (size_t)gi * 64;
#pragma unroll
        for (int kk = 0; kk < 4; kk++)
            af[g][kk] = *(const short8*)&H[kk * 16 + quad * 4];
    }

    for (int m = 0; m < 9; m++) {
        const unsigned short* W = (m < 8) ? (wrel + (size_t)m * 16384) : wroot;
        __syncthreads();
        {
            const uint4* Wg = (const uint4*)W;
#pragma unroll
            for (int i = 0; i < 8; i++) SB4[tid + 256 * i] = Wg[tid + 256 * i];
        }
        __syncthreads();

        float4v ac[NG][8];
#pragma unroll
        for (int g = 0; g < NG; g++)
#pragma unroll
            for (int i = 0; i < 8; i++) ac[g][i] = (float4v){0.f, 0.f, 0.f, 0.f};
#pragma unroll
        for (int kk = 0; kk < 4; kk++) {
#pragma unroll
            for (int ft = 0; ft < 8; ft++) {
                short8 bf = *(const short8*)&SBs[((kk * 8 + ft) * 64 + lane) * 8];
#pragma unroll
                for (int g = 0; g < NG; g++)
                    ac[g][ft] = __builtin_amdgcn_mfma_f32_16x16x32_bf16(af[g][kk], bf, ac[g][ft], 0, 0, 0);
            }
        }

        unsigned* hrm = hr + (size_t)m * NN * 64;
#pragma unroll
        for (int g = 0; g < NG; g++) {
#pragma unroll
            for (int ft = 0; ft < 8; ft++) {
                float4v part;
#pragma unroll
                for (int rg = 0; rg < 4; rg++) part[rg] = __shfl_xor(ac[g][ft][rg], 1, 64);
                if ((ft & 1) == pr) {
                    int a = l15 >> 1;
#pragma unroll
                    for (int rg = 0; rg < 4; rg++) {
                        float lo = pr ? part[rg] : ac[g][ft][rg];
                        float hi = pr ? ac[g][ft][rg] : part[rg];
                        TRp[wave][quad * 4 + rg][ft * 8 + a] = pack2(lo, hi);
                    }
                }
            }
#pragma unroll
            for (int ps = 0; ps < 4; ps++) {
                int ri = ps * 4 + quad;
                uint4 v = *(const uint4*)&TRp[wave][ri][l15 * 4];
                int row = rbase[g] + ri;
                if (row < NN)
                    *(uint4*)&hrm[(size_t)row * 64 + l15 * 4] = v;
            }
        }
    }
}

// ---- launch 2: binB (blocks [0,196)) || mm layer 0 (NG=1) ----
__global__ __launch_bounds__(256) void k_binB_mm(const unsigned* __restrict__ stage,
                                                 const int* __restrict__ bcur,
                                                 int* __restrict__ nodestart,
                                                 unsigned* __restrict__ adj,
                                                 const unsigned* __restrict__ h32,
                                                 const unsigned short* __restrict__ wrel,
                                                 const unsigned short* __restrict__ wroot,
                                                 unsigned* __restrict__ hr) {
    __shared__ uint4 SMEM[3104];   // 49664 B union: binB 37.9 KB | mm 48.5 KB
    int tid = threadIdx.x;
    if (blockIdx.x < NBKT) {
        int* tmp = (int*)SMEM;
        int* lcnt2 = (int*)SMEM + 256;
        int* loff2 = (int*)SMEM + 2304;
        unsigned short* srt2 = (unsigned short*)((int*)SMEM + 4352);
        int* misc = (int*)SMEM + 9472;
        binB_body(stage, bcur, nodestart, adj, blockIdx.x, tid,
                  tmp, lcnt2, loff2, srt2, misc);
    } else {
        mm_body<1>(h32, wrel, wroot, hr, blockIdx.x - NBKT, tid,
                   SMEM, (TRarr*)(SMEM + 2048));
    }
}

__global__ __launch_bounds__(256) void k_mm(const unsigned* __restrict__ h32,
                                            const unsigned short* __restrict__ wrel,
                                            const unsigned short* __restrict__ wroot,
                                            unsigned* __restrict__ hr) {
    __shared__ uint4 SMEM[3104];
    mm_body<2>(h32, wrel, wroot, hr, blockIdx.x, threadIdx.x,
               SMEM, (TRarr*)(SMEM + 2048));
}

// per-edge scaled accumulate: 8 unpack + 8 FMA, scale = 1/deg folded in
#define AGS_A(u, s)                                        \
    a0 += bflo(u.x) * s; a1 += bfhi(u.x) * s;              \
    a2 += bflo(u.y) * s; a3 += bfhi(u.y) * s;              \
    a4 += bflo(u.z) * s; a5 += bfhi(u.z) * s;              \
    a6 += bflo(u.w) * s; a7 += bfhi(u.w) * s;
#define AGS_C(u, s)                                        \
    c0 += bflo(u.x) * s; c1 += bfhi(u.x) * s;              \
    c2 += bflo(u.y) * s; c3 += bfhi(u.y) * s;              \
    c4 += bflo(u.z) * s; c5 += bfhi(u.z) * s;              \
    c6 += bflo(u.w) * s; c7 += bfhi(u.w) * s;

// aggln r12: MERGED relation streams. Edges sorted by (n,r) so each node's
// ~32 edges are ONE contiguous run; adj rec = (r<<28)|(deg<<16)|src is
// self-describing (gather table + mean scale per edge, v_rcp ~1ulp). Kills
// the 8-short-loops structure (8 x E[max4 Poisson(4)] ~ 52 edge-slots ->
// E[max4 Poisson(32)] ~ 40) and its latency-exposed tails. 16-lane quad,
// 16B/lane loads kept (r10: load WIDTH dominates divergence).
__global__ __launch_bounds__(256) void k_aggln(const unsigned* __restrict__ hr,
                                               unsigned* __restrict__ h32,
                                               const unsigned* __restrict__ adj,
                                               const int* __restrict__ nodestart,
                                               const float* __restrict__ bias,
                                               const float* __restrict__ gamma,
                                               const float* __restrict__ beta,
                                               float* __restrict__ out_f,
                                               int add_res, int last) {
    int n = (blockIdx.x * 256 + threadIdx.x) >> 4;   // grid exact: 3125*256/16
    int l15 = threadIdx.x & 15;

    int st = nodestart[n], en = nodestart[n + 1];
    st = st < 0 ? 0 : st;
    en = en > NE ? NE : en;

    float a0 = 0.f, a1 = 0.f, a2 = 0.f, a3 = 0.f,
          a4 = 0.f, a5 = 0.f, a6 = 0.f, a7 = 0.f;
    float c0 = 0.f, c1 = 0.f, c2 = 0.f, c3 = 0.f,
          c4 = 0.f, c5 = 0.f, c6 = 0.f, c7 = 0.f;

    int p = st;
    for (; p + 3 < en; p += 4) {
        unsigned q0 = adj[p],     q1 = adj[p + 1];
        unsigned q2 = adj[p + 2], q3 = adj[p + 3];
        unsigned i0 = (q0 & 0xFFFFu) + (q0 >> 28) * NN;
        unsigned i1 = (q1 & 0xFFFFu) + (q1 >> 28) * NN;
        unsigned i2 = (q2 & 0xFFFFu) + (q2 >> 28) * NN;
        unsigned i3 = (q3 & 0xFFFFu) + (q3 >> 28) * NN;
        uint4 u0 = *(const uint4*)&hr[(size_t)i0 * 64 + l15 * 4];
        uint4 u1 = *(const uint4*)&hr[(size_t)i1 * 64 + l15 * 4];
        uint4 u2 = *(const uint4*)&hr[(size_t)i2 * 64 + l15 * 4];
        uint4 u3 = *(const uint4*)&hr[(size_t)i3 * 64 + l15 * 4];
        float s0 = __builtin_amdgcn_rcpf((float)((q0 >> 16) & 0xFFFu));
        float s1 = __builtin_amdgcn_rcpf((float)((q1 >> 16) & 0xFFFu));
        float s2 = __builtin_amdgcn_rcpf((float)((q2 >> 16) & 0xFFFu));
        float s3 = __builtin_amdgcn_rcpf((float)((q3 >> 16) & 0xFFFu));
        AGS_A(u0, s0) AGS_C(u1, s1) AGS_A(u2, s2) AGS_C(u3, s3)
    }
    for (; p + 1 < en; p += 2) {
        unsigned q0 = adj[p], q1 = adj[p + 1];
        unsigned i0 = (q0 & 0xFFFFu) + (q0 >> 28) * NN;
        unsigned i1 = (q1 & 0xFFFFu) + (q1 >> 28) * NN;
        uint4 u0 = *(const uint4*)&hr[(size_t)i0 * 64 + l15 * 4];
        uint4 u1 = *(const uint4*)&hr[(size_t)i1 * 64 + l15 * 4];
        float s0 = __builtin_amdgcn_rcpf((float)((q0 >> 16) & 0xFFFu));
        float s1 = __builtin_amdgcn_rcpf((float)((q1 >> 16) & 0xFFFu));
        AGS_A(u0, s0) AGS_C(u1, s1)
    }
    if (p < en) {
        unsigned q0 = adj[p];
        unsigned i0 = (q0 & 0xFFFFu) + (q0 >> 28) * NN;
        uint4 u0 = *(const uint4*)&hr[(size_t)i0 * 64 + l15 * 4];
        float s0 = __builtin_amdgcn_rcpf((float)((q0 >> 16) & 0xFFFu));
        AGS_A(u0, s0)
    }

    float t0 = a0 + c0, t1 = a1 + c1, t2 = a2 + c2, t3 = a3 + c3,
          t4 = a4 + c4, t5 = a5 + c5, t6 = a6 + c6, t7 = a7 + c7;

    // root row + bias
    {
        uint4 u = *(const uint4*)&hr[((size_t)8 * NN + n) * 64 + l15 * 4];
        t0 += bflo(u.x); t1 += bfhi(u.x);
        t2 += bflo(u.y); t3 += bfhi(u.y);
        t4 += bflo(u.z); t5 += bfhi(u.z);
        t6 += bflo(u.w); t7 += bfhi(u.w);
    }
    int f0 = 8 * l15;
    {
        float4 b0 = *(const float4*)&bias[f0];
        float4 b1 = *(const float4*)&bias[f0 + 4];
        t0 += b0.x; t1 += b0.y; t2 += b0.z; t3 += b0.w;
        t4 += b1.x; t5 += b1.y; t6 += b1.z; t7 += b1.w;
    }

    float s = t0 + t1 + t2 + t3 + t4 + t5 + t6 + t7;
#pragma unroll
    for (int off = 1; off < 16; off <<= 1) s += __shfl_xor(s, off, 64);
    float mu = s * (1.0f / ND);
    float e0 = t0 - mu, e1 = t1 - mu, e2 = t2 - mu, e3 = t3 - mu,
          e4 = t4 - mu, e5 = t5 - mu, e6 = t6 - mu, e7 = t7 - mu;
    float vs = e0 * e0 + e1 * e1 + e2 * e2 + e3 * e3 +
               e4 * e4 + e5 * e5 + e6 * e6 + e7 * e7;
#pragma unroll
    for (int off = 1; off < 16; off <<= 1) vs += __shfl_xor(vs, off, 64);
    float rr = rsqrtf(vs * (1.0f / ND) + LN_EPS);

    float4 g0 = *(const float4*)&gamma[f0];
    float4 g1 = *(const float4*)&gamma[f0 + 4];
    float4 be0 = *(const float4*)&beta[f0];
    float4 be1 = *(const float4*)&beta[f0 + 4];
    float o0 = fmaxf(e0 * rr * g0.x + be0.x, 0.0f);
    float o1 = fmaxf(e1 * rr * g0.y + be0.y, 0.0f);
    float o2 = fmaxf(e2 * rr * g0.z + be0.z, 0.0f);
    float o3 = fmaxf(e3 * rr * g0.w + be0.w, 0.0f);
    float o4 = fmaxf(e4 * rr * g1.x + be1.x, 0.0f);
    float o5 = fmaxf(e5 * rr * g1.y + be1.y, 0.0f);
    float o6 = fmaxf(e6 * rr * g1.z + be1.z, 0.0f);
    float o7 = fmaxf(e7 * rr * g1.w + be1.w, 0.0f);

    if (add_res) {
        uint4 u = *(const uint4*)&h32[(size_t)n * 64 + l15 * 4];
        o0 += bflo(u.x); o1 += bfhi(u.x);
        o2 += bflo(u.y); o3 += bfhi(u.y);
        o4 += bflo(u.z); o5 += bfhi(u.z);
        o6 += bflo(u.w); o7 += bfhi(u.w);
    }
    if (last) {
        *(float4*)&out_f[(size_t)n * ND + f0] = make_float4(o0, o1, o2, o3);
        *(float4*)&out_f[(size_t)n * ND + f0 + 4] = make_float4(o4, o5, o6, o7);
    } else {
        uint4 w;
        w.x = pack2(o0, o1); w.y = pack2(o2, o3);
        w.z = pack2(o4, o5); w.w = pack2(o6, o7);
        *(uint4*)&h32[(size_t)n * 64 + l15 * 4] = w;
    }
}

extern "C" void kernel_launch(void* const* d_in, const int* in_sizes, int n_in,
                              void* d_out, int out_size, void* d_ws, size_t ws_size,
                              hipStream_t stream) {
    const int*   x      = (const int*)d_in[0];
    const int*   ei     = (const int*)d_in[1];
    const int*   et     = (const int*)d_in[2];
    const float* emb    = (const float*)d_in[3];
    const float* w_rel  = (const float*)d_in[4];
    const float* w_root = (const float*)d_in[5];
    const float* bias   = (const float*)d_in[6];
    const float* gamma  = (const float*)d_in[7];
    const float* beta   = (const float*)d_in[8];
    float* out = (float*)d_out;

    char* ws = (char*)d_ws;
    unsigned* h         = (unsigned*)(ws + WS_H);     // 12.8 MB bf16x2 rows
    int*      nodestart = (int*)     (ws + WS_NS);    // (NN+1) ints
    int*      bcur      = (int*)     (ws + WS_BCUR);  // 784 B
    unsigned* adj       = (unsigned*)(ws + WS_ADJ);   // 6.4 MB packed recs
    unsigned short* wb  = (unsigned short*)(ws + WS_WB);  // 884736 B
    unsigned* big       = (unsigned*)(ws + WS_BIG);   // hr 115.2 MB
    unsigned* stage     = (unsigned*)d_out;           // 8 MB (dead until last aggln)

    const int* src = ei;
    const int* dst = ei + NE;

    hipMemsetAsync(bcur, 0, NBKT * sizeof(int), stream);   // MUST precede binA atomics

    k_prepbin<<<BIN_BLOCKS + PREP_BLOCKS, 256, 0, stream>>>(
        x, emb, w_rel, w_root, src, dst, et, h, wb, bcur, stage);

    k_binB_mm<<<NBKT + MM_BLOCKS_FU, 256, 0, stream>>>(
        stage, bcur, nodestart, adj,
        h, wb, wb + (size_t)24 * 16384, big);
    k_aggln<<<NN * 16 / 256, 256, 0, stream>>>(
        big, h, adj, nodestart,
        bias, gamma, beta, out, 0, 0);
    for (int l = 1; l < NL; l++) {
        k_mm<<<MM_BLOCKS_SA, 256, 0, stream>>>(
            h, wb + (size_t)l * 8 * 16384, wb + (size_t)(24 + l) * 16384, big);
        k_aggln<<<NN * 16 / 256, 256, 0, stream>>>(
            big, h, adj, nodestart,
            bias + l * ND, gamma + l * ND, beta + l * ND,
            out, 1, l == NL - 1);
    }
}

// Round 13
// 493.005 us; speedup vs baseline: 1.2136x; 1.0096x over previous
//
#include <hip/hip_runtime.h>

#define NN 50000
#define NE 1600000
#define NR 8
#define ND 128
#define NL 3
#define RN (NR * NN)
#define LN_EPS 1e-5f

// binning: key = dst*8 + et  (node-major!), bucket = key>>11
#define NBKT 196          // ceil(400000/2048)
#define BSH 11
#define STRIDE_PB 10240   // stage dwords per bucket (mean 8163, +23 sigma)
#define BIN_BLOCKS 1000   // 1600 edges each
#define EPB 1600
#define I4PB 400
#define MM_BLOCKS_SA ((NN + 127) / 128)      // 391 standalone (NG=2)
#define MM_BLOCKS_FU ((NN + 63) / 64)        // 782 fused (NG=1)

#define PREP_G (NN * 64)
#define PREP_W (27 * 16384)
#define PREP_TOT (PREP_G + PREP_W)
#define PREP_BLOCKS ((PREP_TOT + 255) / 256)

// workspace layout
#define WS_H    0
#define WS_NS   14400000     // nodestart: (NN+1) ints
#define WS_BCUR 16000064
#define WS_ADJ  16004096     // 6.4 MB (packed recs)
#define WS_WB   22404096
#define WS_BIG  23288832     // hr: 9 tables = 115.2 MB
// stage lives in d_out (25.6 MB, dead until last aggln overwrites it)

typedef __attribute__((ext_vector_type(8))) short short8;
typedef __attribute__((ext_vector_type(4))) float float4v;

__device__ __forceinline__ float bflo(unsigned u) { return __uint_as_float(u << 16); }
__device__ __forceinline__ float bfhi(unsigned u) { return __uint_as_float(u & 0xFFFF0000u); }
__device__ __forceinline__ unsigned f2bf(float f) {
    unsigned u = __float_as_uint(f);
    return (u + 0x7FFFu + ((u >> 16) & 1u)) >> 16;   // RNE
}
__device__ __forceinline__ unsigned pack2(float lo, float hi) {
    return f2bf(lo) | (f2bf(hi) << 16);
}

// ---- launch 1: binA (blocks [0,1000)) || prep (h gather | wprep) ----
// bcur pre-zeroed on-stream (memset) so binA's atomicAdds are safe (r7 lesson:
// never zero in-grid — block order undefined).
__global__ __launch_bounds__(256) void k_prepbin(const int* __restrict__ x,
                                                 const float* __restrict__ emb,
                                                 const float* __restrict__ w_rel,
                                                 const float* __restrict__ w_root,
                                                 const int* __restrict__ src,
                                                 const int* __restrict__ dst,
                                                 const int* __restrict__ et,
                                                 unsigned* __restrict__ h,
                                                 unsigned short* __restrict__ wb,
                                                 int* __restrict__ bcur,
                                                 unsigned* __restrict__ stage) {
    __shared__ int lcnt[256];
    __shared__ int loff[256];
    __shared__ int lcur[256];
    __shared__ int sbase[256];
    __shared__ int tmp[256];
    __shared__ unsigned srt[EPB];          // 6.4 KB
    __shared__ unsigned char bkt[EPB];     // 1.6 KB

    int tid = threadIdx.x;
    if (blockIdx.x >= BIN_BLOCKS) {
        int i = (blockIdx.x - BIN_BLOCKS) * 256 + tid;
        if (i < PREP_G) {
            int n = i >> 6, dw = i & 63;
            float2 v = *(const float2*)&emb[(size_t)x[n] * ND + 2 * dw];
            h[i] = pack2(v.x, v.y);
            return;
        }
        i -= PREP_G;
        if (i < PREP_W) {
            int m = i >> 14;
            int idx = i & 16383;
            int j = idx & 7;
            int lane = (idx >> 3) & 63;
            int ft = (idx >> 9) & 7;
            int kk = idx >> 12;
            int row = kk * 32 + (lane >> 4) * 8 + j;
            int col = ft * 16 + (lane & 15);
            const float* W = (m < 24) ? (w_rel + (size_t)m * 16384)
                                      : (w_root + (size_t)(m - 24) * 16384);
            wb[i] = (unsigned short)f2bf(W[row * ND + col]);
        }
        return;
    }

    // ---- binA: LDS counting sort by coarse bucket of key = dst*8+et ----
    lcnt[tid] = 0;
    __syncthreads();

    int base4 = blockIdx.x * I4PB;
    const int4* s4p = (const int4*)src;
    const int4* d4p = (const int4*)dst;
    const int4* t4p = (const int4*)et;

    for (int i4 = tid; i4 < I4PB; i4 += 256) {
        int4 d4 = d4p[base4 + i4];
        int4 t4 = t4p[base4 + i4];
        atomicAdd(&lcnt[(d4.x * 8 + t4.x) >> BSH], 1);
        atomicAdd(&lcnt[(d4.y * 8 + t4.y) >> BSH], 1);
        atomicAdd(&lcnt[(d4.z * 8 + t4.z) >> BSH], 1);
        atomicAdd(&lcnt[(d4.w * 8 + t4.w) >> BSH], 1);
    }
    __syncthreads();
    int own = lcnt[tid];
    tmp[tid] = own;
    __syncthreads();
    for (int off = 1; off < 256; off <<= 1) {
        int v = (tid >= off) ? tmp[tid - off] : 0;
        __syncthreads();
        tmp[tid] += v;
        __syncthreads();
    }
    int excl = tmp[tid] - own;
    loff[tid] = excl;
    lcur[tid] = excl;
    if (tid < NBKT) sbase[tid] = atomicAdd(&bcur[tid], own);
    __syncthreads();

    for (int i4 = tid; i4 < I4PB; i4 += 256) {
        int4 s4 = s4p[base4 + i4];
        int4 d4 = d4p[base4 + i4];
        int4 t4 = t4p[base4 + i4];
        int keys[4] = {d4.x * 8 + t4.x, d4.y * 8 + t4.y,
                       d4.z * 8 + t4.z, d4.w * 8 + t4.w};
        int srcs[4] = {s4.x, s4.y, s4.z, s4.w};
#pragma unroll
        for (int j = 0; j < 4; j++) {
            int key = keys[j];
            int b = key >> BSH;
            unsigned rec = ((unsigned)(key & 2047) << 16) | (unsigned)srcs[j];
            int pos = atomicAdd(&lcur[b], 1);
            srt[pos] = rec;
            bkt[pos] = (unsigned char)b;
        }
    }
    __syncthreads();
    for (int i = tid; i < EPB; i += 256) {
        int b = bkt[i];
        int idx = sbase[b] + (i - loff[b]);
        if (idx < STRIDE_PB)                     // insurance: degrade, don't fault
            stage[(size_t)b * STRIDE_PB + idx] = srt[i];
    }
}

// ---- binB: counting sort of bucket's 2048 keys; emits self-describing adj
// recs (r<<28 | deg<<16 | src) and compact nodestart[n] (key%8==0 prefixes).
__device__ __forceinline__ void binB_body(const unsigned* __restrict__ stage,
                                          const int* __restrict__ bcur,
                                          int* __restrict__ nodestart,
                                          unsigned* __restrict__ adj,
                                          int b, int tid,
                                          int* tmp, int* lcnt2, int* loff2,
                                          unsigned short* srt2, int* misc) {
    int bv = (tid < NBKT) ? bcur[tid] : 0;
    tmp[tid] = bv;
    __syncthreads();
    for (int off = 1; off < 256; off <<= 1) {
        int v = (tid >= off) ? tmp[tid - off] : 0;
        __syncthreads();
        tmp[tid] += v;
        __syncthreads();
    }
    if (tid == b) { misc[0] = tmp[tid] - bv; misc[1] = bv; }
    for (int j = tid; j < 2048; j += 256) lcnt2[j] = 0;
    __syncthreads();

    int n = misc[1];
    n = n < STRIDE_PB ? n : STRIDE_PB;           // insurance
    const unsigned* sp = stage + (size_t)b * STRIDE_PB;
    for (int i = tid; i < n; i += 256)
        atomicAdd(&lcnt2[sp[i] >> 16], 1);
    __syncthreads();

    int v8[8];
    int s8 = 0;
    int base8 = tid * 8;
#pragma unroll
    for (int j = 0; j < 8; j++) { v8[j] = lcnt2[base8 + j]; s8 += v8[j]; }
    tmp[tid] = s8;
    __syncthreads();
    for (int off = 1; off < 256; off <<= 1) {
        int v = (tid >= off) ? tmp[tid - off] : 0;
        __syncthreads();
        tmp[tid] += v;
        __syncthreads();
    }
    int run = tmp[tid] - s8;
#pragma unroll
    for (int j = 0; j < 8; j++) { loff2[base8 + j] = run; run += v8[j]; }
    __syncthreads();
    for (int j = tid; j < 2048; j += 256) lcnt2[j] = loff2[j];   // cursor
    __syncthreads();

    for (int i = tid; i < n; i += 256) {
        unsigned rec = sp[i];
        int pos = atomicAdd(&lcnt2[rec >> 16], 1);
        srt2[pos] = (unsigned short)(rec & 0xFFFFu);
    }
    __syncthreads();

    int gb = misc[0];
    int segbase = b << BSH;
#pragma unroll
    for (int jj = 0; jj < 8; jj++) {
        int j = base8 + jj;
        int key = segbase + j;
        if (key >= RN) break;
        int s = loff2[j], e = lcnt2[j];
        int d = e - s; d = d > 4095 ? 4095 : d;
        unsigned tag = ((unsigned)(key & 7) << 28) | ((unsigned)d << 16);
        for (int i = s; i < e; i++) adj[gb + i] = tag | (unsigned)srt2[i];
        if ((key & 7) == 0) nodestart[key >> 3] = gb + s;
    }
    if (b == NBKT - 1 && tid == 0) nodestart[NN] = NE;
}

typedef unsigned TRarr[16][66];

// ---- mm: NG row-groups (64 rows) per block. r13: W staged in TWO 16 KB
// halves (kk{0,1} then kk{2,3}) — accumulators persist, LDS drops
// 48.5->32.5 KB (fused 49.7->37.9) => 4 blocks/CU instead of 3 (occ 20->27%).
// Cost: 4 barriers/m instead of 2.
template <int NG>
__device__ __forceinline__ void mm_body(const unsigned* __restrict__ h32,
                                        const unsigned short* __restrict__ wrel,
                                        const unsigned short* __restrict__ wroot,
                                        unsigned* __restrict__ hr,
                                        int mb, int tid,
                                        uint4* SB4, TRarr* TRp) {
    const unsigned short* SBs = (const unsigned short*)SB4;
    int wave = tid >> 6, lane = tid & 63;
    int quad = lane >> 4, l15 = lane & 15;
    int pr = l15 & 1;

    int rbase[NG];
    short8 af[NG][4];
#pragma unroll
    for (int g = 0; g < NG; g++) {
        rbase[g] = mb * (64 * NG) + g * 64 + wave * 16;
        int gi = rbase[g] + l15; gi = gi < NN ? gi : NN - 1;
        const unsigned* H = h32 + (size_t)gi * 64;
#pragma unroll
        for (int kk = 0; kk < 4; kk++)
            af[g][kk] = *(const short8*)&H[kk * 16 + quad * 4];
    }

    for (int m = 0; m < 9; m++) {
        const unsigned short* W = (m < 8) ? (wrel + (size_t)m * 16384) : wroot;
        const uint4* Wg = (const uint4*)W;

        float4v ac[NG][8];
#pragma unroll
        for (int g = 0; g < NG; g++)
#pragma unroll
            for (int i = 0; i < 8; i++) ac[g][i] = (float4v){0.f, 0.f, 0.f, 0.f};

#pragma unroll
        for (int half = 0; half < 2; half++) {
            __syncthreads();                         // prev stage's reads done
#pragma unroll
            for (int i = 0; i < 4; i++)
                SB4[tid + 256 * i] = Wg[half * 1024 + tid + 256 * i];
            __syncthreads();
#pragma unroll
            for (int kloc = 0; kloc < 2; kloc++) {
                int kk = half * 2 + kloc;
#pragma unroll
                for (int ft = 0; ft < 8; ft++) {
                    short8 bf = *(const short8*)&SBs[((kloc * 8 + ft) * 64 + lane) * 8];
#pragma unroll
                    for (int g = 0; g < NG; g++)
                        ac[g][ft] = __builtin_amdgcn_mfma_f32_16x16x32_bf16(af[g][kk], bf, ac[g][ft], 0, 0, 0);
                }
            }
        }

        unsigned* hrm = hr + (size_t)m * NN * 64;
#pragma unroll
        for (int g = 0; g < NG; g++) {
            // pack + wave-private transpose (no barrier: same-wave order)
#pragma unroll
            for (int ft = 0; ft < 8; ft++) {
                float4v part;
#pragma unroll
                for (int rg = 0; rg < 4; rg++) part[rg] = __shfl_xor(ac[g][ft][rg], 1, 64);
                if ((ft & 1) == pr) {
                    int a = l15 >> 1;
#pragma unroll
                    for (int rg = 0; rg < 4; rg++) {
                        float lo = pr ? part[rg] : ac[g][ft][rg];
                        float hi = pr ? ac[g][ft][rg] : part[rg];
                        TRp[wave][quad * 4 + rg][ft * 8 + a] = pack2(lo, hi);
                    }
                }
            }
#pragma unroll
            for (int ps = 0; ps < 4; ps++) {
                int ri = ps * 4 + quad;
                uint4 v = *(const uint4*)&TRp[wave][ri][l15 * 4];
                int row = rbase[g] + ri;
                if (row < NN)
                    *(uint4*)&hrm[(size_t)row * 64 + l15 * 4] = v;
            }
        }
    }
}

// ---- launch 2: binB (blocks [0,196)) || mm layer 0 (NG=1) ----
// SMEM union 37.9 KB (binB 37.9 | mm 32.5) => 4 blocks/CU.
__global__ __launch_bounds__(256) void k_binB_mm(const unsigned* __restrict__ stage,
                                                 const int* __restrict__ bcur,
                                                 int* __restrict__ nodestart,
                                                 unsigned* __restrict__ adj,
                                                 const unsigned* __restrict__ h32,
                                                 const unsigned short* __restrict__ wrel,
                                                 const unsigned short* __restrict__ wroot,
                                                 unsigned* __restrict__ hr) {
    __shared__ uint4 SMEM[2369];   // 37904 B
    int tid = threadIdx.x;
    if (blockIdx.x < NBKT) {
        int* tmp = (int*)SMEM;
        int* lcnt2 = (int*)SMEM + 256;
        int* loff2 = (int*)SMEM + 2304;
        unsigned short* srt2 = (unsigned short*)((int*)SMEM + 4352);
        int* misc = (int*)SMEM + 9472;
        binB_body(stage, bcur, nodestart, adj, blockIdx.x, tid,
                  tmp, lcnt2, loff2, srt2, misc);
    } else {
        mm_body<1>(h32, wrel, wroot, hr, blockIdx.x - NBKT, tid,
                   SMEM, (TRarr*)(SMEM + 1024));
    }
}

__global__ __launch_bounds__(256) void k_mm(const unsigned* __restrict__ h32,
                                            const unsigned short* __restrict__ wrel,
                                            const unsigned short* __restrict__ wroot,
                                            unsigned* __restrict__ hr) {
    __shared__ uint4 SMEM[2080];   // 33280 B => 4 blocks/CU
    mm_body<2>(h32, wrel, wroot, hr, blockIdx.x, threadIdx.x,
               SMEM, (TRarr*)(SMEM + 1024));
}

// per-edge scaled accumulate: 8 unpack + 8 FMA, scale = 1/deg folded in
#define AGS_A(u, s)                                        \
    a0 += bflo(u.x) * s; a1 += bfhi(u.x) * s;              \
    a2 += bflo(u.y) * s; a3 += bfhi(u.y) * s;              \
    a4 += bflo(u.z) * s; a5 += bfhi(u.z) * s;              \
    a6 += bflo(u.w) * s; a7 += bfhi(u.w) * s;
#define AGS_C(u, s)                                        \
    c0 += bflo(u.x) * s; c1 += bfhi(u.x) * s;              \
    c2 += bflo(u.y) * s; c3 += bfhi(u.y) * s;              \
    c4 += bflo(u.z) * s; c5 += bfhi(u.z) * s;              \
    c6 += bflo(u.w) * s; c7 += bfhi(u.w) * s;

// aggln (r12 merged-stream form, at its gather floor): edges sorted by (n,r),
// one contiguous run per node; rec = (r<<28)|(deg<<16)|src self-describing;
// mean folded in via v_rcp per edge; 16-lane quad, 16B/lane loads (r10 lesson).
__global__ __launch_bounds__(256) void k_aggln(const unsigned* __restrict__ hr,
                                               unsigned* __restrict__ h32,
                                               const unsigned* __restrict__ adj,
                                               const int* __restrict__ nodestart,
                                               const float* __restrict__ bias,
                                               const float* __restrict__ gamma,
                                               const float* __restrict__ beta,
                                               float* __restrict__ out_f,
                                               int add_res, int last) {
    int n = (blockIdx.x * 256 + threadIdx.x) >> 4;   // grid exact: 3125*256/16
    int l15 = threadIdx.x & 15;

    int st = nodestart[n], en = nodestart[n + 1];
    st = st < 0 ? 0 : st;
    en = en > NE ? NE : en;

    float a0 = 0.f, a1 = 0.f, a2 = 0.f, a3 = 0.f,
          a4 = 0.f, a5 = 0.f, a6 = 0.f, a7 = 0.f;
    float c0 = 0.f, c1 = 0.f, c2 = 0.f, c3 = 0.f,
          c4 = 0.f, c5 = 0.f, c6 = 0.f, c7 = 0.f;

    int p = st;
    for (; p + 3 < en; p += 4) {
        unsigned q0 = adj[p],     q1 = adj[p + 1];
        unsigned q2 = adj[p + 2], q3 = adj[p + 3];
        unsigned i0 = (q0 & 0xFFFFu) + (q0 >> 28) * NN;
        unsigned i1 = (q1 & 0xFFFFu) + (q1 >> 28) * NN;
        unsigned i2 = (q2 & 0xFFFFu) + (q2 >> 28) * NN;
        unsigned i3 = (q3 & 0xFFFFu) + (q3 >> 28) * NN;
        uint4 u0 = *(const uint4*)&hr[(size_t)i0 * 64 + l15 * 4];
        uint4 u1 = *(const uint4*)&hr[(size_t)i1 * 64 + l15 * 4];
        uint4 u2 = *(const uint4*)&hr[(size_t)i2 * 64 + l15 * 4];
        uint4 u3 = *(const uint4*)&hr[(size_t)i3 * 64 + l15 * 4];
        float s0 = __builtin_amdgcn_rcpf((float)((q0 >> 16) & 0xFFFu));
        float s1 = __builtin_amdgcn_rcpf((float)((q1 >> 16) & 0xFFFu));
        float s2 = __builtin_amdgcn_rcpf((float)((q2 >> 16) & 0xFFFu));
        float s3 = __builtin_amdgcn_rcpf((float)((q3 >> 16) & 0xFFFu));
        AGS_A(u0, s0) AGS_C(u1, s1) AGS_A(u2, s2) AGS_C(u3, s3)
    }
    for (; p + 1 < en; p += 2) {
        unsigned q0 = adj[p], q1 = adj[p + 1];
        unsigned i0 = (q0 & 0xFFFFu) + (q0 >> 28) * NN;
        unsigned i1 = (q1 & 0xFFFFu) + (q1 >> 28) * NN;
        uint4 u0 = *(const uint4*)&hr[(size_t)i0 * 64 + l15 * 4];
        uint4 u1 = *(const uint4*)&hr[(size_t)i1 * 64 + l15 * 4];
        float s0 = __builtin_amdgcn_rcpf((float)((q0 >> 16) & 0xFFFu));
        float s1 = __builtin_amdgcn_rcpf((float)((q1 >> 16) & 0xFFFu));
        AGS_A(u0, s0) AGS_C(u1, s1)
    }
    if (p < en) {
        unsigned q0 = adj[p];
        unsigned i0 = (q0 & 0xFFFFu) + (q0 >> 28) * NN;
        uint4 u0 = *(const uint4*)&hr[(size_t)i0 * 64 + l15 * 4];
        float s0 = __builtin_amdgcn_rcpf((float)((q0 >> 16) & 0xFFFu));
        AGS_A(u0, s0)
    }

    float t0 = a0 + c0, t1 = a1 + c1, t2 = a2 + c2, t3 = a3 + c3,
          t4 = a4 + c4, t5 = a5 + c5, t6 = a6 + c6, t7 = a7 + c7;

    // root row + bias
    {
        uint4 u = *(const uint4*)&hr[((size_t)8 * NN + n) * 64 + l15 * 4];
        t0 += bflo(u.x); t1 += bfhi(u.x);
        t2 += bflo(u.y); t3 += bfhi(u.y);
        t4 += bflo(u.z); t5 += bfhi(u.z);
        t6 += bflo(u.w); t7 += bfhi(u.w);
    }
    int f0 = 8 * l15;
    {
        float4 b0 = *(const float4*)&bias[f0];
        float4 b1 = *(const float4*)&bias[f0 + 4];
        t0 += b0.x; t1 += b0.y; t2 += b0.z; t3 += b0.w;
        t4 += b1.x; t5 += b1.y; t6 += b1.z; t7 += b1.w;
    }

    float s = t0 + t1 + t2 + t3 + t4 + t5 + t6 + t7;
#pragma unroll
    for (int off = 1; off < 16; off <<= 1) s += __shfl_xor(s, off, 64);
    float mu = s * (1.0f / ND);
    float e0 = t0 - mu, e1 = t1 - mu, e2 = t2 - mu, e3 = t3 - mu,
          e4 = t4 - mu, e5 = t5 - mu, e6 = t6 - mu, e7 = t7 - mu;
    float vs = e0 * e0 + e1 * e1 + e2 * e2 + e3 * e3 +
               e4 * e4 + e5 * e5 + e6 * e6 + e7 * e7;
#pragma unroll
    for (int off = 1; off < 16; off <<= 1) vs += __shfl_xor(vs, off, 64);
    float rr = rsqrtf(vs * (1.0f / ND) + LN_EPS);

    float4 g0 = *(const float4*)&gamma[f0];
    float4 g1 = *(const float4*)&gamma[f0 + 4];
    float4 be0 = *(const float4*)&beta[f0];
    float4 be1 = *(const float4*)&beta[f0 + 4];
    float o0 = fmaxf(e0 * rr * g0.x + be0.x, 0.0f);
    float o1 = fmaxf(e1 * rr * g0.y + be0.y, 0.0f);
    float o2 = fmaxf(e2 * rr * g0.z + be0.z, 0.0f);
    float o3 = fmaxf(e3 * rr * g0.w + be0.w, 0.0f);
    float o4 = fmaxf(e4 * rr * g1.x + be1.x, 0.0f);
    float o5 = fmaxf(e5 * rr * g1.y + be1.y, 0.0f);
    float o6 = fmaxf(e6 * rr * g1.z + be1.z, 0.0f);
    float o7 = fmaxf(e7 * rr * g1.w + be1.w, 0.0f);

    if (add_res) {
        uint4 u = *(const uint4*)&h32[(size_t)n * 64 + l15 * 4];
        o0 += bflo(u.x); o1 += bfhi(u.x);
        o2 += bflo(u.y); o3 += bfhi(u.y);
        o4 += bflo(u.z); o5 += bfhi(u.z);
        o6 += bflo(u.w); o7 += bfhi(u.w);
    }
    if (last) {
        *(float4*)&out_f[(size_t)n * ND + f0] = make_float4(o0, o1, o2, o3);
        *(float4*)&out_f[(size_t)n * ND + f0 + 4] = make_float4(o4, o5, o6, o7);
    } else {
        uint4 w;
        w.x = pack2(o0, o1); w.y = pack2(o2, o3);
        w.z = pack2(o4, o5); w.w = pack2(o6, o7);
        *(uint4*)&h32[(size_t)n * 64 + l15 * 4] = w;
    }
}

extern "C" void kernel_launch(void* const* d_in, const int* in_sizes, int n_in,
                              void* d_out, int out_size, void* d_ws, size_t ws_size,
                              hipStream_t stream) {
    const int*   x      = (const int*)d_in[0];
    const int*   ei     = (const int*)d_in[1];
    const int*   et     = (const int*)d_in[2];
    const float* emb    = (const float*)d_in[3];
    const float* w_rel  = (const float*)d_in[4];
    const float* w_root = (const float*)d_in[5];
    const float* bias   = (const float*)d_in[6];
    const float* gamma  = (const float*)d_in[7];
    const float* beta   = (const float*)d_in[8];
    float* out = (float*)d_out;

    char* ws = (char*)d_ws;
    unsigned* h         = (unsigned*)(ws + WS_H);     // 12.8 MB bf16x2 rows
    int*      nodestart = (int*)     (ws + WS_NS);    // (NN+1) ints
    int*      bcur      = (int*)     (ws + WS_BCUR);  // 784 B
    unsigned* adj       = (unsigned*)(ws + WS_ADJ);   // 6.4 MB packed recs
    unsigned short* wb  = (unsigned short*)(ws + WS_WB);  // 884736 B
    unsigned* big       = (unsigned*)(ws + WS_BIG);   // hr 115.2 MB
    unsigned* stage     = (unsigned*)d_out;           // 8 MB (dead until last aggln)

    const int* src = ei;
    const int* dst = ei + NE;

    hipMemsetAsync(bcur, 0, NBKT * sizeof(int), stream);   // MUST precede binA atomics

    k_prepbin<<<BIN_BLOCKS + PREP_BLOCKS, 256, 0, stream>>>(
        x, emb, w_rel, w_root, src, dst, et, h, wb, bcur, stage);

    k_binB_mm<<<NBKT + MM_BLOCKS_FU, 256, 0, stream>>>(
        stage, bcur, nodestart, adj,
        h, wb, wb + (size_t)24 * 16384, big);
    k_aggln<<<NN * 16 / 256, 256, 0, stream>>>(
        big, h, adj, nodestart,
        bias, gamma, beta, out, 0, 0);
    for (int l = 1; l < NL; l++) {
        k_mm<<<MM_BLOCKS_SA, 256, 0, stream>>>(
            h, wb + (size_t)l * 8 * 16384, wb + (size_t)(24 + l) * 16384, big);
        k_aggln<<<NN * 16 / 256, 256, 0, stream>>>(
            big, h, adj, nodestart,
            bias + l * ND, gamma + l * ND, beta + l * ND,
            out, 1, l == NL - 1);
    }
}